// Round 15
// baseline (4148.430 us; speedup 1.0000x reference)
//
#include <hip/hip_runtime.h>

#define BB 2
#define TT 2048
#define DD 1024
#define HH 16
#define LL 12
#define VV 50257
#define VP 50432            // V padded to multiple of 256
#define HDD 64
#define FF 4096
#define MM (BB*TT)          // 4096 rows
#define QS 3072             // fused qkv row stride

typedef __bf16 bf16;
typedef __bf16 bf16x8 __attribute__((ext_vector_type(8)));
typedef __bf16 bf16x4 __attribute__((ext_vector_type(4)));
typedef __bf16 bf16x2 __attribute__((ext_vector_type(2)));
typedef float  f32x4  __attribute__((ext_vector_type(4)));
typedef float  f32x4u __attribute__((ext_vector_type(4), aligned(4)));
typedef unsigned int u32x4 __attribute__((ext_vector_type(4)));

typedef const __attribute__((address_space(1))) void* gas_t;
typedef __attribute__((address_space(3))) void* las_t;

// ---------------------------------------------------------------- embedding
__global__ __launch_bounds__(256) void k_embed(const int* __restrict__ x,
    const float* __restrict__ tok, const float* __restrict__ pos,
    float* __restrict__ h)
{
    int row = blockIdx.x;
    int t   = row & (TT - 1);
    int idx = x[row];
    int c   = threadIdx.x * 4;
    float4 a = *(const float4*)(tok + (size_t)idx * DD + c);
    float4 p = *(const float4*)(pos + (size_t)t   * DD + c);
    a.x += p.x; a.y += p.y; a.z += p.z; a.w += p.w;
    *(float4*)(h + (size_t)row * DD + c) = a;
}

// ---------------------------------------------------------------- residual-add layernorm
// Wave-per-row: 4 rows/block, 64 lanes/row, 16 elems/lane (4 x f32x4 at
// k*256 + lane*4). Pure shfl reduction — no LDS, no barriers.
__global__ __launch_bounds__(256) void k_lnadd(const float* __restrict__ resf,
    const bf16* __restrict__ delta,
    const float* __restrict__ g, const float* __restrict__ b,
    float* __restrict__ outf, bf16* __restrict__ outb)
{
    int tid = threadIdx.x, lane = tid & 63, wid = tid >> 6;
    int row = blockIdx.x * 4 + wid;
    const float* rp = resf + (size_t)row * DD;

    float4 v[4];
    #pragma unroll
    for (int k = 0; k < 4; k++) {
        int c = k * 256 + lane * 4;
        v[k] = *(const float4*)(rp + c);
        if (delta) {
            bf16x4 d4 = *(const bf16x4*)(delta + (size_t)row * DD + c);
            v[k].x += (float)d4[0]; v[k].y += (float)d4[1];
            v[k].z += (float)d4[2]; v[k].w += (float)d4[3];
        }
    }
    float s = 0.f, s2 = 0.f;
    #pragma unroll
    for (int k = 0; k < 4; k++) {
        s  += v[k].x + v[k].y + v[k].z + v[k].w;
        s2 += v[k].x*v[k].x + v[k].y*v[k].y + v[k].z*v[k].z + v[k].w*v[k].w;
    }
    #pragma unroll
    for (int d = 1; d < 64; d <<= 1) { s += __shfl_xor(s, d); s2 += __shfl_xor(s2, d); }
    float mean = s * (1.0f / DD);
    float var  = s2 * (1.0f / DD) - mean * mean;
    float inv  = 1.0f / sqrtf(var + 1e-5f);

    #pragma unroll
    for (int k = 0; k < 4; k++) {
        int c = k * 256 + lane * 4;
        float4 gg = *(const float4*)(g + c);
        float4 bb = *(const float4*)(b + c);
        float o0 = (v[k].x - mean) * inv * gg.x + bb.x;
        float o1 = (v[k].y - mean) * inv * gg.y + bb.y;
        float o2 = (v[k].z - mean) * inv * gg.z + bb.z;
        float o3 = (v[k].w - mean) * inv * gg.w + bb.w;
        size_t o = (size_t)row * DD + c;
        if (outf) { float4 r = {o0, o1, o2, o3}; *(float4*)(outf + o) = r; }
        if (outb) {
            bf16x4 r4 = {(bf16)o0, (bf16)o1, (bf16)o2, (bf16)o3};
            *(bf16x4*)(outb + o) = r4;
        }
    }
}

// ---------------------------------------------------------------- weight transpose+convert
__global__ __launch_bounds__(256) void k_wtrans(
    const float* __restrict__ src, bf16* __restrict__ dst,
    int K, int N, int Npad, size_t srcLS, size_t dstLS)
{
    src += (size_t)blockIdx.z * srcLS;
    dst += (size_t)blockIdx.z * dstLS;
    int k0 = blockIdx.y * 32, n0 = blockIdx.x * 256;
    __shared__ float tile[32][256];
    int tid = threadIdx.x;
    #pragma unroll
    for (int p = 0; p < 8; p++) {
        int kk = p * 4 + (tid >> 6);
        int nn = (tid & 63) * 4;
        const float* sp = src + (size_t)(k0 + kk) * N + n0 + nn;
        f32x4u v = {0.f, 0.f, 0.f, 0.f};
        if (n0 + nn + 3 < N) {
            v = *(const f32x4u*)sp;            // dwordx4, 4B-align OK
        } else {
            #pragma unroll
            for (int i = 0; i < 4; i++)
                if (n0 + nn + i < N) v[i] = sp[i];
        }
        *(f32x4*)&tile[kk][nn] = v;
    }
    __syncthreads();
    int n = n0 + tid;
    if (n < Npad) {
        bf16 rowv[32];
        #pragma unroll
        for (int kk = 0; kk < 32; kk++) rowv[kk] = (bf16)tile[kk][tid];
        bf16* dp = dst + (size_t)n * K + k0;
        #pragma unroll
        for (int s = 0; s < 4; s++)
            *(bf16x8*)(dp + s * 8) = *(const bf16x8*)&rowv[s * 8];
    }
}

// ---------------------------------------------------------------- bias merge (q|k|v)
__global__ __launch_bounds__(256) void k_biasmerge(
    const float* __restrict__ bq, const float* __restrict__ bk,
    const float* __restrict__ bv, float* __restrict__ dst)
{
    int i = blockIdx.x * 256 + threadIdx.x;
    if (i >= LL * QS) return;
    int l = i / QS, j = i % QS;
    float v = (j < 1024) ? bq[l*1024 + j]
            : (j < 2048) ? bk[l*1024 + j - 1024]
                         : bv[l*1024 + j - 2048];
    dst[i] = v;
}

// ================================================================ GEMM epilogue (shared)
#define GEMM_EPILOGUE(MI_CNT, WM_STRIDE)                                        \
    bool nalign = ((Nout & 3) == 0);                                            \
    _Pragma("unroll")                                                           \
    for (int mi = 0; mi < MI_CNT; mi++) {                                       \
        int row = m0 + wm*WM_STRIDE + mi*16 + r16;                              \
        _Pragma("unroll")                                                       \
        for (int ni = 0; ni < 4; ni++) {                                        \
            int col0 = n0 + wn*64 + ni*16 + g4*4;                               \
            f32x4 v = acc[mi][ni];                                              \
            float sc = (qpre && col0 < 1024) ? 0.125f : 1.0f;                   \
            if (col0 + 3 < Nout) {                                              \
                if (bias) {                                                     \
                    float4 bi = *(const float4*)(bias + col0);                  \
                    v[0] += bi.x; v[1] += bi.y; v[2] += bi.z; v[3] += bi.w;     \
                }                                                               \
                if (res) {                                                      \
                    float4 rr = *(const float4*)(res + (size_t)row*Nout + col0);\
                    v[0] += rr.x; v[1] += rr.y; v[2] += rr.z; v[3] += rr.w;     \
                }                                                               \
                if (relu) { _Pragma("unroll")                                   \
                    for (int j = 0; j < 4; j++) v[j] = fmaxf(v[j], 0.0f); }     \
                if (outf) {                                                     \
                    float* p = outf + (size_t)row * Nout + col0;                \
                    if (nalign) *(f32x4*)p = v; else *(f32x4u*)p = v;           \
                }                                                               \
                if (outb) {                                                     \
                    bf16x4 o4 = {(bf16)(v[0]*sc), (bf16)(v[1]*sc),              \
                                 (bf16)(v[2]*sc), (bf16)(v[3]*sc)};             \
                    *(bf16x4*)(outb + (size_t)row * Nout + col0) = o4;          \
                }                                                               \
            } else {                                                            \
                _Pragma("unroll")                                               \
                for (int j = 0; j < 4; j++) {                                   \
                    int col = col0 + j;                                         \
                    if (col >= Nout) continue;                                  \
                    float vv = v[j] + (bias ? bias[col] : 0.0f);                \
                    if (res)  vv += res[(size_t)row * Nout + col];              \
                    if (relu) vv = fmaxf(vv, 0.0f);                             \
                    if (outf) outf[(size_t)row * Nout + col] = vv;              \
                    if (outb) outb[(size_t)row * Nout + col] = (bf16)(vv*sc);   \
                }                                                               \
            }                                                                   \
        }                                                                       \
    }

#define BARS { __builtin_amdgcn_sched_barrier(0); __builtin_amdgcn_s_barrier(); }

// ---------------------------------------------------------------- GEMM MTx128 (4-phase)
#define STG2(nn, kk)                                                            \
    do { const int k0_ = (nn)*64 + (kk)*32; const int db_ = (nn)&1;             \
        _Pragma("unroll") for (int i_ = 0; i_ < AL; i_++) {                     \
            int a_ = i_*2048 + tid*8;                                           \
            int sr_ = a_>>6, x_ = (a_&63) ^ ((sr_&7)<<3);                       \
            int r_ = 2*sr_ + (x_>>5), e_ = x_&31;                               \
            __builtin_amdgcn_global_load_lds(                                   \
                (gas_t)(A + (size_t)(m0+r_)*K + k0_+e_),                        \
                (las_t)&lA[db_][kk][a_], 16, 0, 0);                             \
        }                                                                       \
        _Pragma("unroll") for (int i_ = 0; i_ < 2; i_++) {                      \
            int a_ = i_*2048 + tid*8;                                           \
            int sr_ = a_>>6, x_ = (a_&63) ^ ((sr_&7)<<3);                       \
            int r_ = 2*sr_ + (x_>>5), e_ = x_&31;                               \
            __builtin_amdgcn_global_load_lds(                                   \
                (gas_t)(BT + (size_t)(n0+r_)*K + k0_+e_),                       \
                (las_t)&lB[db_][kk][a_], 16, 0, 0);                             \
        }                                                                       \
    } while (0)

#define WAITG                                                                   \
    { if constexpr (MT == 128) asm volatile("s_waitcnt vmcnt(4)" ::: "memory"); \
      else                     asm volatile("s_waitcnt vmcnt(3)" ::: "memory"); }

#define PH2(nn, kk, sn, sk, wv)                                                 \
    { const int db_ = (nn)&1;                                                   \
        bf16x8 af[MI], bfr[4];                                                  \
        _Pragma("unroll") for (int mi = 0; mi < MI; mi++) {                     \
            int row_ = wm*(MT/2) + mi*16 + r16;                                 \
            int sr_ = row_>>1;                                                  \
            int xp_ = (((row_&1)<<5) | kfrag) ^ ((sr_&7)<<3);                   \
            af[mi] = *(const bf16x8*)&lA[db_][kk][sr_*64 + xp_];                \
        }                                                                       \
        _Pragma("unroll") for (int ni = 0; ni < 4; ni++) {                      \
            int row_ = wn*64 + ni*16 + r16;                                     \
            int sr_ = row_>>1;                                                  \
            int xp_ = (((row_&1)<<5) | kfrag) ^ ((sr_&7)<<3);                   \
            bfr[ni] = *(const bf16x8*)&lB[db_][kk][sr_*64 + xp_];               \
        }                                                                       \
        bool st_ = (sn) < nt;                                                   \
        if (st_) STG2(sn, sk);                                                  \
        BARS;                                                                   \
        __builtin_amdgcn_s_setprio(1);                                          \
        _Pragma("unroll") for (int mi = 0; mi < MI; mi++)                       \
            _Pragma("unroll") for (int ni = 0; ni < 4; ni++)                    \
                acc[mi][ni] = __builtin_amdgcn_mfma_f32_16x16x32_bf16(          \
                    bfr[ni], af[mi], acc[mi][ni], 0, 0, 0);                     \
        __builtin_amdgcn_s_setprio(0);                                          \
        if (wv) { if (st_) WAITG                                                \
                  else     asm volatile("s_waitcnt vmcnt(0)" ::: "memory"); }   \
        BARS;                                                                   \
    }

template<int MT>
__global__ __launch_bounds__(256) void k_gemm2t(
    const bf16* __restrict__ A, const bf16* __restrict__ BT,
    const float* __restrict__ bias, const float* __restrict__ res,
    float* __restrict__ outf, bf16* __restrict__ outb,
    int K, int Nout, int relu, int mswap, int qpre)
{
    constexpr int AL = MT / 64;        // A loads per stage group
    constexpr int MI = MT / 32;        // mi fragments per wave
    __shared__ alignas(16) bf16 lA[2][2][MT * 32];
    __shared__ alignas(16) bf16 lB[2][2][128 * 32];
    int tid = threadIdx.x;
    int lane = tid & 63, w = tid >> 6;
    int wm = w >> 1, wn = w & 1;
    int nb = mswap ? blockIdx.y : blockIdx.x;
    int mb = mswap ? blockIdx.x : blockIdx.y;
    int n0 = nb * 128, m0 = mb * MT;
    int r16 = lane & 15, g4 = lane >> 4;
    int kfrag = g4 * 8;

    f32x4 acc[MI][4];
    const f32x4 fzero = {0.f, 0.f, 0.f, 0.f};
    #pragma unroll
    for (int i = 0; i < MI; i++)
        #pragma unroll
        for (int j = 0; j < 4; j++) acc[i][j] = fzero;

    int nt = K >> 6;
    STG2(0, 0); STG2(0, 1); STG2(1, 0);
    WAITG
    BARS;
    for (int it2 = 0; it2 < nt; it2 += 2) {
        PH2(it2,     0, it2 + 1, 1, 0);
        PH2(it2,     1, it2 + 2, 0, 1);
        PH2(it2 + 1, 0, it2 + 2, 1, 0);
        PH2(it2 + 1, 1, it2 + 3, 0, 1);
    }
    GEMM_EPILOGUE(MI, (MT/2))
}

// ================================================================ GEMM 256x256, 8-phase
#define SA3(tile, u)                                                            \
    do { int s_ = tid*8; int rl_ = s_>>6;                                       \
        int x_ = (s_&63) ^ ((rl_&7)<<3);                                        \
        __builtin_amdgcn_global_load_lds(                                       \
            (gas_t)(A + (size_t)(m0 + (u)*64 + rl_)*K + (size_t)(tile)*64 + x_),\
            (las_t)&lA3[(tile)&1][(u)*4096 + s_], 16, 0, 0);                    \
    } while (0)
#define SB3(tile, v)                                                            \
    do { int s_ = tid*8; int rl_ = s_>>6; int lr_ = (v)*64 + rl_;               \
        int r_ = (lr_ < 128) ? ((lr_&31) + ((lr_>>5)<<6))                       \
                             : (32 + ((lr_-128)&31) + (((lr_-128)>>5)<<6));     \
        int x_ = (s_&63) ^ ((rl_&7)<<3);                                        \
        __builtin_amdgcn_global_load_lds(                                       \
            (gas_t)(BT + (size_t)(n0 + r_)*K + (size_t)(tile)*64 + x_),         \
            (las_t)&lB3[(tile)&1][(v)*4096 + s_], 16, 0, 0);                    \
    } while (0)
#define RDA3(dst, mig, mi, kh) { int lr_ = wm*128 + ((mig)*4+(mi))*16 + r16;    \
    dst = *(const bf16x8*)&lA3[db_][lr_*64 + ((((kh)*32) | kfrag) ^ ((lr_&7)<<3))]; }
#define RDB3(dst, ni, kh) { int lr_ = wn*32 + (((ni)&1)<<4) + r16 + (((ni)>=2)?128:0); \
    dst = *(const bf16x8*)&lB3[db_][lr_*64 + ((((kh)*32) | kfrag) ^ ((lr_&7)<<3))]; }
#define MF3(mb_, nb_)                                                           \
    _Pragma("unroll") for (int kh = 0; kh < 2; kh++)                            \
        _Pragma("unroll") for (int mi = 0; mi < 4; mi++)                        \
            _Pragma("unroll") for (int ni = 0; ni < 2; ni++)                    \
                acc[(mb_)+mi][(nb_)+ni] = __builtin_amdgcn_mfma_f32_16x16x32_bf16( \
                    bfr[(nb_)+ni][kh], afr[mi][kh], acc[(mb_)+mi][(nb_)+ni], 0, 0, 0);

#define QUAD3(nn, cs, sn)                                                       \
    { const int db_ = (nn)&1;                                                   \
      /* P1 */                                                                  \
      _Pragma("unroll") for (int mi=0;mi<4;mi++){RDA3(afr[mi][0],0,mi,0);RDA3(afr[mi][1],0,mi,1);} \
      _Pragma("unroll") for (int ni=0;ni<2;ni++){RDB3(bfr[ni][0],ni,0);RDB3(bfr[ni][1],ni,1);}     \
      BARS;                                                                     \
      __builtin_amdgcn_s_setprio(1); MF3(0,0); __builtin_amdgcn_s_setprio(0);   \
      BARS;                                                                     \
      /* P2 */                                                                  \
      _Pragma("unroll") for (int ni=2;ni<4;ni++){RDB3(bfr[ni][0],ni,0);RDB3(bfr[ni][1],ni,1);}     \
      if (cs) { SA3(sn,0); SA3(sn,2); }                                         \
      BARS;                                                                     \
      __builtin_amdgcn_s_setprio(1); MF3(0,2); __builtin_amdgcn_s_setprio(0);   \
      BARS;                                                                     \
      /* P3 */                                                                  \
      _Pragma("unroll") for (int mi=0;mi<4;mi++){RDA3(afr[mi][0],1,mi,0);RDA3(afr[mi][1],1,mi,1);} \
      if (cs) { SB3(sn,0); SB3(sn,1); SB3(sn,2); SB3(sn,3); }                   \
      BARS;                                                                     \
      __builtin_amdgcn_s_setprio(1); MF3(4,0); __builtin_amdgcn_s_setprio(0);   \
      BARS;                                                                     \
      /* P4 */                                                                  \
      if (cs) { SA3(sn,1); SA3(sn,3); }                                         \
      BARS;                                                                     \
      __builtin_amdgcn_s_setprio(1); MF3(4,2); __builtin_amdgcn_s_setprio(0);   \
      if (cs) asm volatile("s_waitcnt vmcnt(8)" ::: "memory");                  \
      else    asm volatile("s_waitcnt vmcnt(0)" ::: "memory");                  \
      BARS; }

__global__ __launch_bounds__(512, 2) void k_gemm3(
    const bf16* __restrict__ A, const bf16* __restrict__ BT,
    const float* __restrict__ bias, const float* __restrict__ res,
    float* __restrict__ outf, bf16* __restrict__ outb,
    int K, int Nout, int relu, int mswap, int qpre)
{
    __shared__ alignas(16) bf16 lA3[2][256 * 64];
    __shared__ alignas(16) bf16 lB3[2][256 * 64];
    int tid = threadIdx.x;
    int lane = tid & 63, w = tid >> 6;
    int wm = w >> 2, wn = w & 3;           // 2M x 4N waves
    int nb = mswap ? blockIdx.y : blockIdx.x;
    int mb = mswap ? blockIdx.x : blockIdx.y;
    int n0 = nb * 256, m0 = mb * 256;
    int r16 = lane & 15, g4 = lane >> 4;
    int kfrag = g4 * 8;

    f32x4 acc[8][4];
    const f32x4 fzero = {0.f, 0.f, 0.f, 0.f};
    #pragma unroll
    for (int i = 0; i < 8; i++)
        #pragma unroll
        for (int j = 0; j < 4; j++) acc[i][j] = fzero;

    bf16x8 afr[4][2];
    bf16x8 bfr[4][2];

    int nt = K >> 6;
    SA3(0,0); SA3(0,1); SA3(0,2); SA3(0,3);
    SB3(0,0); SB3(0,1); SB3(0,2); SB3(0,3);
    SA3(1,0); SA3(1,1); SA3(1,2); SA3(1,3);
    SB3(1,0); SB3(1,1); SB3(1,2); SB3(1,3);
    asm volatile("s_waitcnt vmcnt(8)" ::: "memory");
    BARS;
    for (int it2 = 0; it2 < nt; it2 += 2) {
        bool c2 = (it2 + 2 < nt), c3 = (it2 + 3 < nt);
        QUAD3(it2,     c2, it2 + 2);
        QUAD3(it2 + 1, c3, it2 + 3);
    }
    GEMM_EPILOGUE(8, 128)
}

// ---------------------------------------------------------------- fallback GEMM (f32 B)
__global__ __launch_bounds__(256) void k_gemm_f32b(
    const bf16* __restrict__ A, const float* __restrict__ Bm,
    const float* __restrict__ bias, float* __restrict__ outf,
    int M, int N, int K)
{
    __shared__ alignas(16) bf16 lA[128][40];
    __shared__ alignas(16) bf16 lB[128][40];
    int tid  = threadIdx.x;
    int lane = tid & 63, wid = tid >> 6;
    int wm = wid >> 1, wn = wid & 1;
    int m0 = blockIdx.x * 128, n0 = blockIdx.y * 128;
    int r16 = lane & 15, g4 = lane >> 4;

    f32x4 acc[4][4];
    const f32x4 fzero = {0.f, 0.f, 0.f, 0.f};
    #pragma unroll
    for (int i = 0; i < 4; i++)
        #pragma unroll
        for (int j = 0; j < 4; j++) acc[i][j] = fzero;

    int arow = tid >> 2, aseg = tid & 3;
    int bkr  = tid >> 3, bnb  = tid & 7;
    bool nfull = (n0 + 128 <= N);

    for (int k0 = 0; k0 < K; k0 += 32) {
        *(uint4*)&lA[arow][aseg*8] =
            *(const uint4*)(A + (size_t)(m0 + arow) * K + k0 + aseg*8);
        *(uint4*)&lA[arow + 64][aseg*8] =
            *(const uint4*)(A + (size_t)(m0 + arow + 64) * K + k0 + aseg*8);
        const float* bsrc = Bm + (size_t)(k0 + bkr) * N + n0;
        #pragma unroll
        for (int q = 0; q < 4; q++) {
            int n = q*32 + bnb*4;
            #pragma unroll
            for (int i = 0; i < 4; i++) {
                float fv = 0.0f;
                if (nfull || (n0 + n + i < N)) fv = bsrc[n + i];
                lB[n+i][bkr] = (bf16)fv;
            }
        }
        __syncthreads();
        int kb = g4 * 8;
        bf16x8 af[4], bfr[4];
        #pragma unroll
        for (int mi = 0; mi < 4; mi++)
            af[mi] = *(const bf16x8*)&lA[wm*64 + mi*16 + r16][kb];
        #pragma unroll
        for (int ni = 0; ni < 4; ni++)
            bfr[ni] = *(const bf16x8*)&lB[wn*64 + ni*16 + r16][kb];
        #pragma unroll
        for (int mi = 0; mi < 4; mi++)
            #pragma unroll
            for (int ni = 0; ni < 4; ni++)
                acc[mi][ni] = __builtin_amdgcn_mfma_f32_16x16x32_bf16(
                    af[mi], bfr[ni], acc[mi][ni], 0, 0, 0);
        __syncthreads();
    }

    #pragma unroll
    for (int ni = 0; ni < 4; ni++) {
        int col = n0 + wn*64 + ni*16 + r16;
        if (col >= N) continue;
        float bi = bias[col];
        #pragma unroll
        for (int mi = 0; mi < 4; mi++) {
            #pragma unroll
            for (int j = 0; j < 4; j++) {
                int row = m0 + wm*64 + mi*16 + g4*4 + j;
                outf[(size_t)row * N + col] = acc[mi][ni][j] + bi;
            }
        }
    }
}

// ---------------------------------------------------------------- attention v4
// LPT-paired causal blocks: grid (TT/256, B*H); block i handles q-tiles i and
// (15-i) -> uniform 17 KV-tiles per block, 256 blocks = 1/CU.
__global__ __launch_bounds__(512) void k_attn4(
    const bf16* __restrict__ qkv, bf16* __restrict__ o)
{
    __shared__ alignas(16) bf16 lK[64][72];    // [s][k] natural, padded
    __shared__ alignas(16) bf16 lVT[64][72];   // [d][s], s-block XOR swizzle
    int tid = threadIdx.x, lane = tid & 63, w = tid >> 6;
    int r16 = lane & 15, g4 = lane >> 4;
    int ib = blockIdx.x;                       // 0..7
    int bh = blockIdx.y, bb = bh >> 4, hh = bh & 15;
    const bf16* base = qkv + (size_t)bb * TT * QS + hh * HDD;
    const bf16* kp = base + 1024;
    const bf16* vp = base + 2048;
    bf16* op = o + (size_t)bb * TT * DD + hh * HDD;

    int krow = tid >> 3, kseg = tid & 7;
    int vsp  = tid >> 4, vseg = tid & 15;
    const f32x4 fzero = {0.f, 0.f, 0.f, 0.f};

    #pragma unroll 1
    for (int pass = 0; pass < 2; pass++) {
        int tb = pass ? (TT/128 - 1 - ib) : ib;
        int t0 = tb * 128;
        int qrow = t0 + w * 16;

        bf16x8 qf0, qf1;
        {
            const bf16* qr = base + (size_t)(qrow + r16) * QS + g4 * 8;
            qf0 = *(const bf16x8*)qr;
            qf1 = *(const bf16x8*)(qr + 32);
        }
        f32x4 oacc[4];
        #pragma unroll
        for (int i = 0; i < 4; i++) oacc[i] = fzero;
        float mrun = -1e30f, lrun = 0.f;

        int send = t0 + 128;
        bf16x8 kr;
        bf16x4 va4, vb4;
        {
            kr  = *(const bf16x8*)(kp + (size_t)krow * QS + kseg * 8);
            va4 = *(const bf16x4*)(vp + (size_t)(2*vsp) * QS + vseg * 4);
            vb4 = *(const bf16x4*)(vp + (size_t)(2*vsp) * QS + QS + vseg * 4);
        }

        for (int s0 = 0; s0 < send; s0 += 64) {
            __syncthreads();   // LDS free (prev compute done)
            *(bf16x8*)&lK[krow][kseg*8] = kr;
            #pragma unroll
            for (int i = 0; i < 4; i++) {
                int d = vseg*4 + i;
                int mpr = (vsp >> 2) ^ (d >> 3);
                bf16x2 pv2 = {va4[i], vb4[i]};
                *(unsigned int*)&lVT[d][mpr*8 + (vsp&3)*2] =
                    __builtin_bit_cast(unsigned int, pv2);
            }
            if (s0 + 64 < send) {
                kr  = *(const bf16x8*)(kp + (size_t)(s0 + 64 + krow) * QS + kseg * 8);
                va4 = *(const bf16x4*)(vp + (size_t)(s0 + 64 + 2*vsp) * QS + vseg * 4);
                vb4 = *(const bf16x4*)(vp + (size_t)(s0 + 64 + 2*vsp) * QS + QS + vseg * 4);
            }
            __syncthreads();   // LDS ready

            if (s0 <= qrow + 15) {
                f32x4 sf[4];
                __builtin_amdgcn_s_setprio(1);
                #pragma unroll
                for (int nf = 0; nf < 4; nf++) {
                    sf[nf] = fzero;
                    bf16x8 kf0 = *(const bf16x8*)&lK[nf*16 + r16][g4*8];
                    bf16x8 kf1 = *(const bf16x8*)&lK[nf*16 + r16][32 + g4*8];
                    sf[nf] = __builtin_amdgcn_mfma_f32_16x16x32_bf16(kf0, qf0, sf[nf], 0, 0, 0);
                    sf[nf] = __builtin_amdgcn_mfma_f32_16x16x32_bf16(kf1, qf1, sf[nf], 0, 0, 0);
                }
                __builtin_amdgcn_s_setprio(0);
                int qa = qrow + r16;
                if (s0 + 63 > qrow) {
                    #pragma unroll
                    for (int nf = 0; nf < 4; nf++)
                        #pragma unroll
                        for (int j = 0; j < 4; j++)
                            if (s0 + nf*16 + g4*4 + j > qa) sf[nf][j] = -1e30f;
                }
                float pm = sf[0][0];
                #pragma unroll
                for (int nf = 0; nf < 4; nf++)
                    #pragma unroll
                    for (int j = 0; j < 4; j++) pm = fmaxf(pm, sf[nf][j]);
                pm = fmaxf(pm, __shfl_xor(pm, 16));
                pm = fmaxf(pm, __shfl_xor(pm, 32));
                bool defer = (__all(pm - mrun <= 8.0f) != 0);
                float al = 1.0f;
                if (!defer) {
                    float mn = fmaxf(mrun, pm);
                    al = __expf(mrun - mn);
                    mrun = mn;
                }
                float ps = 0.f;
                #pragma unroll
                for (int nf = 0; nf < 4; nf++)
                    #pragma unroll
                    for (int j = 0; j < 4; j++) {
                        float p = __expf(sf[nf][j] - mrun);
                        sf[nf][j] = p;
                        ps += p;
                    }
                ps += __shfl_xor(ps, 16);
                ps += __shfl_xor(ps, 32);
                lrun = lrun * al + ps;
                if (!defer) {
                    #pragma unroll
                    for (int nf = 0; nf < 4; nf++)
                        #pragma unroll
                        for (int j = 0; j < 4; j++) oacc[nf][j] *= al;
                }
                unsigned int pk[4][2];
                #pragma unroll
                for (int nf = 0; nf < 4; nf++) {
                    bf16x2 a = {(bf16)sf[nf][0], (bf16)sf[nf][1]};
                    bf16x2 b = {(bf16)sf[nf][2], (bf16)sf[nf][3]};
                    pk[nf][0] = __builtin_bit_cast(unsigned int, a);
                    pk[nf][1] = __builtin_bit_cast(unsigned int, b);
                }
                int srcA = r16 + (2*(g4 & 1))*16;
                int srcB = srcA + 16;
                bool hi2 = (g4 >= 2);
                __builtin_amdgcn_s_setprio(1);
                #pragma unroll
                for (int c = 0; c < 2; c++) {
                    unsigned int a0 = __shfl(pk[2*c  ][0], srcA);
                    unsigned int a1 = __shfl(pk[2*c+1][0], srcA);
                    unsigned int b0 = __shfl(pk[2*c  ][1], srcA);
                    unsigned int b1 = __shfl(pk[2*c+1][1], srcA);
                    unsigned int e0 = __shfl(pk[2*c  ][0], srcB);
                    unsigned int e1 = __shfl(pk[2*c+1][0], srcB);
                    unsigned int f0 = __shfl(pk[2*c  ][1], srcB);
                    unsigned int f1 = __shfl(pk[2*c+1][1], srcB);
                    u32x4 uu = { hi2 ? a1 : a0, hi2 ? b1 : b0,
                                 hi2 ? e1 : e0, hi2 ? f1 : f0 };
                    bf16x8 pf = __builtin_bit_cast(bf16x8, uu);
                    #pragma unroll
                    for (int nf = 0; nf < 4; nf++) {
                        int d = nf*16 + r16;
                        int mread = (4*c + g4) ^ (d >> 3);
                        bf16x8 vt = *(const bf16x8*)&lVT[d][mread*8];
                        oacc[nf] = __builtin_amdgcn_mfma_f32_16x16x32_bf16(
                            vt, pf, oacc[nf], 0, 0, 0);
                    }
                }
                __builtin_amdgcn_s_setprio(0);
            }
        }

        float inv = 1.0f / lrun;
        #pragma unroll
        for (int nf = 0; nf < 4; nf++) {
            f32x4 ov = oacc[nf];
            bf16x4 o4 = {(bf16)(ov[0]*inv), (bf16)(ov[1]*inv),
                         (bf16)(ov[2]*inv), (bf16)(ov[3]*inv)};
            *(bf16x4*)(op + (size_t)(qrow + r16) * DD + nf*16 + g4*4) = o4;
        }
    }
}

// ---------------------------------------------------------------- launcher
extern "C" void kernel_launch(void* const* d_in, const int* in_sizes, int n_in,
                              void* d_out, int out_size, void* d_ws, size_t ws_size,
                              hipStream_t stream)
{
    (void)in_sizes; (void)n_in; (void)out_size;
    const int*   x    = (const int*)  d_in[0];
    const float* tok  = (const float*)d_in[1];
    const float* pos  = (const float*)d_in[2];
    const float* ln1g = (const float*)d_in[3];
    const float* ln1b = (const float*)d_in[4];
    const float* wq   = (const float*)d_in[5];
    const float* bq   = (const float*)d_in[6];
    const float* wk   = (const float*)d_in[7];
    const float* bk   = (const float*)d_in[8];
    const float* wv   = (const float*)d_in[9];
    const float* bv   = (const float*)d_in[10];
    const float* wo   = (const float*)d_in[11];
    const float* bo   = (const float*)d_in[12];
    const float* ln2g = (const float*)d_in[13];
    const float* ln2b = (const float*)d_in[14];
    const float* w1   = (const float*)d_in[15];
    const float* b1   = (const float*)d_in[16];
    const float* w2   = (const float*)d_in[17];
    const float* b2   = (const float*)d_in[18];
    const float* lnfg = (const float*)d_in[19];
    const float* lnfb = (const float*)d_in[20];
    const float* fcw  = (const float*)d_in[21];
    const float* fcb  = (const float*)d_in[22];

    const size_t MB = (size_t)1 << 20;
    char*  sb   = (char*)d_out;
    float* hA   = (float*)(sb);                    // 16 MB  (LN1 f32 out)
    float* hB   = (float*)(sb + 16*MB);            // 16 MB  (embed out / LN2 f32 out)
    bf16*  hnb  = (bf16*) (sb + 32*MB);            //  8 MB  (LN bf16 out, GEMM A)
    bf16*  qkv  = (bf16*) (sb + 40*MB);            // 24 MB  [4096][3072]
    bf16*  obuf = (bf16*) (sb + 64*MB);            //  8 MB  (attn out)
    bf16*  pb   = (bf16*) (sb + 72*MB);            //  8 MB  (proj delta)
    bf16*  f1b  = (bf16*) (sb + 80*MB);            // 32 MB  (FFN hidden)
    bf16*  fout = (bf16*) (sb + 112*MB);           //  8 MB  (FFN2 delta)
    bf16*  WT   = (bf16*) (sb + 120*MB);           // 288 MB packed B^T -> ends 408
    float* bqkv = (float*)(sb + 408*MB);           // 147 KB
    bf16*  hfb  = (bf16*) d_ws;                    //  8 MB  (survives logits write)

    const size_t LWT = 12582912;                   // per-layer WT elems (24 MB)
    const size_t FCWT_BYTES = (size_t)VP * DD * 2; // 103.3 MB
    bool fast_logits = (ws_size >= 8*MB + FCWT_BYTES);
    bf16* fcwT = (bf16*)((char*)d_ws + 8*MB);

    dim3 blk(256);
    dim3 blk512(512);

    // ---- weight prepack (B^T bf16) ----
    k_wtrans<<<dim3(4, 32, 12), blk, 0, stream>>>(wq, WT,               DD, DD, DD, (size_t)DD*DD, LWT);
    k_wtrans<<<dim3(4, 32, 12), blk, 0, stream>>>(wk, WT + 1024*1024,   DD, DD, DD, (size_t)DD*DD, LWT);
    k_wtrans<<<dim3(4, 32, 12), blk, 0, stream>>>(wv, WT + 2048*1024,   DD, DD, DD, (size_t)DD*DD, LWT);
    k_wtrans<<<dim3(4, 32, 12), blk, 0, stream>>>(wo, WT + 3145728,     DD, DD, DD, (size_t)DD*DD, LWT);
    k_wtrans<<<dim3(16, 32, 12), blk, 0, stream>>>(w1, WT + 4194304,    DD, FF, FF, (size_t)DD*FF, LWT);
    k_wtrans<<<dim3(4, 128, 12), blk, 0, stream>>>(w2, WT + 8388608,    FF, DD, DD, (size_t)FF*DD, LWT);
    if (fast_logits)
        k_wtrans<<<dim3(VP/256, 32, 1), blk, 0, stream>>>(fcw, fcwT, DD, VV, VP, 0, 0);
    k_biasmerge<<<dim3(144), blk, 0, stream>>>(bq, bk, bv, bqkv);

    // ---- trunk (residual-add fused into LN) ----
    k_embed<<<MM, blk, 0, stream>>>(x, tok, pos, hB);
    for (int l = 0; l < LL; l++) {
        const bf16* WTl = WT + (size_t)l * LWT;
        k_lnadd<<<MM/4, blk, 0, stream>>>(hB, l ? fout : nullptr,
                                          ln1g + l*DD, ln1b + l*DD, hA, hnb);
        k_gemm2t<128><<<dim3(24, 32), blk, 0, stream>>>(hnb, WTl, bqkv + l*QS,
                                                  nullptr, nullptr, qkv, DD, QS, 0, 0, 1);
        k_attn4<<<dim3(TT/256, BB*HH), blk512, 0, stream>>>(qkv, obuf);
        k_gemm2t<64><<<dim3(8, 64), blk, 0, stream>>>(obuf, WTl + 3145728, bo + l*DD,
                                                 nullptr, nullptr, pb, DD, DD, 0, 0, 0);
        k_lnadd<<<MM/4, blk, 0, stream>>>(hA, pb, ln2g + l*DD, ln2b + l*DD, hB, hnb);
        k_gemm3<<<dim3(FF/256, MM/256), blk512, 0, stream>>>(hnb, WTl + 4194304, b1 + l*FF,
                                                  nullptr, nullptr, f1b, DD, FF, 1, 0, 0);
        k_gemm2t<128><<<dim3(8, 32), blk, 0, stream>>>(f1b, WTl + 8388608, b2 + l*DD,
                                                 nullptr, nullptr, fout, FF, DD, 0, 0, 0);
    }
    k_lnadd<<<MM/4, blk, 0, stream>>>(hB, fout, lnfg, lnfb, nullptr, hfb);

    // ---- logits (m-fastest grid, regular stores) ----
    if (fast_logits) {
        k_gemm3<<<dim3(MM/256, VP/256), blk512, 0, stream>>>(hfb, fcwT, fcb,
                                                      nullptr, (float*)d_out, nullptr,
                                                      DD, VV, 0, 1, 0);
    } else {
        k_gemm_f32b<<<dim3(32, (VV + 127)/128), blk, 0, stream>>>(hfb, fcw, fcb,
                                                                  (float*)d_out, MM, VV, DD);
    }
}

// Round 16
// 4045.020 us; speedup vs baseline: 1.0256x; 1.0256x over previous
//
#include <hip/hip_runtime.h>

#define BB 2
#define TT 2048
#define DD 1024
#define HH 16
#define LL 12
#define VV 50257
#define VP 50432            // V padded to multiple of 256
#define HDD 64
#define FF 4096
#define MM (BB*TT)          // 4096 rows
#define QS 3072             // fused qkv row stride

typedef __bf16 bf16;
typedef __bf16 bf16x8 __attribute__((ext_vector_type(8)));
typedef __bf16 bf16x4 __attribute__((ext_vector_type(4)));
typedef __bf16 bf16x2 __attribute__((ext_vector_type(2)));
typedef float  f32x4  __attribute__((ext_vector_type(4)));
typedef float  f32x4u __attribute__((ext_vector_type(4), aligned(4)));
typedef unsigned int u32x4 __attribute__((ext_vector_type(4)));

typedef const __attribute__((address_space(1))) void* gas_t;
typedef __attribute__((address_space(3))) void* las_t;

// ---------------------------------------------------------------- embedding
__global__ __launch_bounds__(256) void k_embed(const int* __restrict__ x,
    const float* __restrict__ tok, const float* __restrict__ pos,
    float* __restrict__ h)
{
    int row = blockIdx.x;
    int t   = row & (TT - 1);
    int idx = x[row];
    int c   = threadIdx.x * 4;
    float4 a = *(const float4*)(tok + (size_t)idx * DD + c);
    float4 p = *(const float4*)(pos + (size_t)t   * DD + c);
    a.x += p.x; a.y += p.y; a.z += p.z; a.w += p.w;
    *(float4*)(h + (size_t)row * DD + c) = a;
}

// ---------------------------------------------------------------- residual-add layernorm
// Wave-per-row: 4 rows/block, 64 lanes/row, 16 elems/lane. No LDS, no barriers.
__global__ __launch_bounds__(256) void k_lnadd(const float* __restrict__ resf,
    const bf16* __restrict__ delta,
    const float* __restrict__ g, const float* __restrict__ b,
    float* __restrict__ outf, bf16* __restrict__ outb)
{
    int tid = threadIdx.x, lane = tid & 63, wid = tid >> 6;
    int row = blockIdx.x * 4 + wid;
    const float* rp = resf + (size_t)row * DD;

    float4 v[4];
    #pragma unroll
    for (int k = 0; k < 4; k++) {
        int c = k * 256 + lane * 4;
        v[k] = *(const float4*)(rp + c);
        if (delta) {
            bf16x4 d4 = *(const bf16x4*)(delta + (size_t)row * DD + c);
            v[k].x += (float)d4[0]; v[k].y += (float)d4[1];
            v[k].z += (float)d4[2]; v[k].w += (float)d4[3];
        }
    }
    float s = 0.f, s2 = 0.f;
    #pragma unroll
    for (int k = 0; k < 4; k++) {
        s  += v[k].x + v[k].y + v[k].z + v[k].w;
        s2 += v[k].x*v[k].x + v[k].y*v[k].y + v[k].z*v[k].z + v[k].w*v[k].w;
    }
    #pragma unroll
    for (int d = 1; d < 64; d <<= 1) { s += __shfl_xor(s, d); s2 += __shfl_xor(s2, d); }
    float mean = s * (1.0f / DD);
    float var  = s2 * (1.0f / DD) - mean * mean;
    float inv  = 1.0f / sqrtf(var + 1e-5f);

    #pragma unroll
    for (int k = 0; k < 4; k++) {
        int c = k * 256 + lane * 4;
        float4 gg = *(const float4*)(g + c);
        float4 bb = *(const float4*)(b + c);
        float o0 = (v[k].x - mean) * inv * gg.x + bb.x;
        float o1 = (v[k].y - mean) * inv * gg.y + bb.y;
        float o2 = (v[k].z - mean) * inv * gg.z + bb.z;
        float o3 = (v[k].w - mean) * inv * gg.w + bb.w;
        size_t o = (size_t)row * DD + c;
        if (outf) { float4 r = {o0, o1, o2, o3}; *(float4*)(outf + o) = r; }
        if (outb) {
            bf16x4 r4 = {(bf16)o0, (bf16)o1, (bf16)o2, (bf16)o3};
            *(bf16x4*)(outb + o) = r4;
        }
    }
}

// ---------------------------------------------------------------- weight transpose+convert
__global__ __launch_bounds__(256) void k_wtrans(
    const float* __restrict__ src, bf16* __restrict__ dst,
    int K, int N, int Npad, size_t srcLS, size_t dstLS)
{
    src += (size_t)blockIdx.z * srcLS;
    dst += (size_t)blockIdx.z * dstLS;
    int k0 = blockIdx.y * 32, n0 = blockIdx.x * 256;
    __shared__ float tile[32][256];
    int tid = threadIdx.x;
    #pragma unroll
    for (int p = 0; p < 8; p++) {
        int kk = p * 4 + (tid >> 6);
        int nn = (tid & 63) * 4;
        const float* sp = src + (size_t)(k0 + kk) * N + n0 + nn;
        f32x4u v = {0.f, 0.f, 0.f, 0.f};
        if (n0 + nn + 3 < N) {
            v = *(const f32x4u*)sp;            // dwordx4, 4B-align OK
        } else {
            #pragma unroll
            for (int i = 0; i < 4; i++)
                if (n0 + nn + i < N) v[i] = sp[i];
        }
        *(f32x4*)&tile[kk][nn] = v;
    }
    __syncthreads();
    int n = n0 + tid;
    if (n < Npad) {
        bf16 rowv[32];
        #pragma unroll
        for (int kk = 0; kk < 32; kk++) rowv[kk] = (bf16)tile[kk][tid];
        bf16* dp = dst + (size_t)n * K + k0;
        #pragma unroll
        for (int s = 0; s < 4; s++)
            *(bf16x8*)(dp + s * 8) = *(const bf16x8*)&rowv[s * 8];
    }
}

// ---------------------------------------------------------------- bias merge (q|k|v)
__global__ __launch_bounds__(256) void k_biasmerge(
    const float* __restrict__ bq, const float* __restrict__ bk,
    const float* __restrict__ bv, float* __restrict__ dst)
{
    int i = blockIdx.x * 256 + threadIdx.x;
    if (i >= LL * QS) return;
    int l = i / QS, j = i % QS;
    float v = (j < 1024) ? bq[l*1024 + j]
            : (j < 2048) ? bk[l*1024 + j - 1024]
                         : bv[l*1024 + j - 2048];
    dst[i] = v;
}

// ================================================================ GEMM epilogue (shared)
#define GEMM_EPILOGUE(MI_CNT, WM_STRIDE)                                        \
    bool nalign = ((Nout & 3) == 0);                                            \
    _Pragma("unroll")                                                           \
    for (int mi = 0; mi < MI_CNT; mi++) {                                       \
        int row = m0 + wm*WM_STRIDE + mi*16 + r16;                              \
        _Pragma("unroll")                                                       \
        for (int ni = 0; ni < 4; ni++) {                                        \
            int col0 = n0 + wn*64 + ni*16 + g4*4;                               \
            f32x4 v = acc[mi][ni];                                              \
            float sc = (qpre && col0 < 1024) ? 0.125f : 1.0f;                   \
            if (col0 + 3 < Nout) {                                              \
                if (bias) {                                                     \
                    float4 bi = *(const float4*)(bias + col0);                  \
                    v[0] += bi.x; v[1] += bi.y; v[2] += bi.z; v[3] += bi.w;     \
                }                                                               \
                if (res) {                                                      \
                    float4 rr = *(const float4*)(res + (size_t)row*Nout + col0);\
                    v[0] += rr.x; v[1] += rr.y; v[2] += rr.z; v[3] += rr.w;     \
                }                                                               \
                if (relu) { _Pragma("unroll")                                   \
                    for (int j = 0; j < 4; j++) v[j] = fmaxf(v[j], 0.0f); }     \
                if (outf) {                                                     \
                    float* p = outf + (size_t)row * Nout + col0;                \
                    if (nalign) *(f32x4*)p = v; else *(f32x4u*)p = v;           \
                }                                                               \
                if (outb) {                                                     \
                    bf16x4 o4 = {(bf16)(v[0]*sc), (bf16)(v[1]*sc),              \
                                 (bf16)(v[2]*sc), (bf16)(v[3]*sc)};             \
                    *(bf16x4*)(outb + (size_t)row * Nout + col0) = o4;          \
                }                                                               \
            } else {                                                            \
                _Pragma("unroll")                                               \
                for (int j = 0; j < 4; j++) {                                   \
                    int col = col0 + j;                                         \
                    if (col >= Nout) continue;                                  \
                    float vv = v[j] + (bias ? bias[col] : 0.0f);                \
                    if (res)  vv += res[(size_t)row * Nout + col];              \
                    if (relu) vv = fmaxf(vv, 0.0f);                             \
                    if (outf) outf[(size_t)row * Nout + col] = vv;              \
                    if (outb) outb[(size_t)row * Nout + col] = (bf16)(vv*sc);   \
                }                                                               \
            }                                                                   \
        }                                                                       \
    }

#define BARS { __builtin_amdgcn_sched_barrier(0); __builtin_amdgcn_s_barrier(); }

// ---------------------------------------------------------------- GEMM MTx128 (4-phase)
#define STG2(nn, kk)                                                            \
    do { const int k0_ = (nn)*64 + (kk)*32; const int db_ = (nn)&1;             \
        _Pragma("unroll") for (int i_ = 0; i_ < AL; i_++) {                     \
            int a_ = i_*2048 + tid*8;                                           \
            int sr_ = a_>>6, x_ = (a_&63) ^ ((sr_&7)<<3);                       \
            int r_ = 2*sr_ + (x_>>5), e_ = x_&31;                               \
            __builtin_amdgcn_global_load_lds(                                   \
                (gas_t)(A + (size_t)(m0+r_)*K + k0_+e_),                        \
                (las_t)&lA[db_][kk][a_], 16, 0, 0);                             \
        }                                                                       \
        _Pragma("unroll") for (int i_ = 0; i_ < 2; i_++) {                      \
            int a_ = i_*2048 + tid*8;                                           \
            int sr_ = a_>>6, x_ = (a_&63) ^ ((sr_&7)<<3);                       \
            int r_ = 2*sr_ + (x_>>5), e_ = x_&31;                               \
            __builtin_amdgcn_global_load_lds(                                   \
                (gas_t)(BT + (size_t)(n0+r_)*K + k0_+e_),                       \
                (las_t)&lB[db_][kk][a_], 16, 0, 0);                             \
        }                                                                       \
    } while (0)

#define WAITG                                                                   \
    { if constexpr (MT == 128) asm volatile("s_waitcnt vmcnt(4)" ::: "memory"); \
      else                     asm volatile("s_waitcnt vmcnt(3)" ::: "memory"); }

#define PH2(nn, kk, sn, sk, wv)                                                 \
    { const int db_ = (nn)&1;                                                   \
        bf16x8 af[MI], bfr[4];                                                  \
        _Pragma("unroll") for (int mi = 0; mi < MI; mi++) {                     \
            int row_ = wm*(MT/2) + mi*16 + r16;                                 \
            int sr_ = row_>>1;                                                  \
            int xp_ = (((row_&1)<<5) | kfrag) ^ ((sr_&7)<<3);                   \
            af[mi] = *(const bf16x8*)&lA[db_][kk][sr_*64 + xp_];                \
        }                                                                       \
        _Pragma("unroll") for (int ni = 0; ni < 4; ni++) {                      \
            int row_ = wn*64 + ni*16 + r16;                                     \
            int sr_ = row_>>1;                                                  \
            int xp_ = (((row_&1)<<5) | kfrag) ^ ((sr_&7)<<3);                   \
            bfr[ni] = *(const bf16x8*)&lB[db_][kk][sr_*64 + xp_];               \
        }                                                                       \
        bool st_ = (sn) < nt;                                                   \
        if (st_) STG2(sn, sk);                                                  \
        BARS;                                                                   \
        __builtin_amdgcn_s_setprio(1);                                          \
        _Pragma("unroll") for (int mi = 0; mi < MI; mi++)                       \
            _Pragma("unroll") for (int ni = 0; ni < 4; ni++)                    \
                acc[mi][ni] = __builtin_amdgcn_mfma_f32_16x16x32_bf16(          \
                    bfr[ni], af[mi], acc[mi][ni], 0, 0, 0);                     \
        __builtin_amdgcn_s_setprio(0);                                          \
        if (wv) { if (st_) WAITG                                                \
                  else     asm volatile("s_waitcnt vmcnt(0)" ::: "memory"); }   \
        BARS;                                                                   \
    }

template<int MT>
__global__ __launch_bounds__(256) void k_gemm2t(
    const bf16* __restrict__ A, const bf16* __restrict__ BT,
    const float* __restrict__ bias, const float* __restrict__ res,
    float* __restrict__ outf, bf16* __restrict__ outb,
    int K, int Nout, int relu, int mswap, int qpre)
{
    constexpr int AL = MT / 64;        // A loads per stage group
    constexpr int MI = MT / 32;        // mi fragments per wave
    __shared__ alignas(16) bf16 lA[2][2][MT * 32];
    __shared__ alignas(16) bf16 lB[2][2][128 * 32];
    int tid = threadIdx.x;
    int lane = tid & 63, w = tid >> 6;
    int wm = w >> 1, wn = w & 1;
    int nb = mswap ? blockIdx.y : blockIdx.x;
    int mb = mswap ? blockIdx.x : blockIdx.y;
    int n0 = nb * 128, m0 = mb * MT;
    int r16 = lane & 15, g4 = lane >> 4;
    int kfrag = g4 * 8;

    f32x4 acc[MI][4];
    const f32x4 fzero = {0.f, 0.f, 0.f, 0.f};
    #pragma unroll
    for (int i = 0; i < MI; i++)
        #pragma unroll
        for (int j = 0; j < 4; j++) acc[i][j] = fzero;

    int nt = K >> 6;
    STG2(0, 0); STG2(0, 1); STG2(1, 0);
    WAITG
    BARS;
    for (int it2 = 0; it2 < nt; it2 += 2) {
        PH2(it2,     0, it2 + 1, 1, 0);
        PH2(it2,     1, it2 + 2, 0, 1);
        PH2(it2 + 1, 0, it2 + 2, 1, 0);
        PH2(it2 + 1, 1, it2 + 3, 0, 1);
    }
    GEMM_EPILOGUE(MI, (MT/2))
}

// ================================================================ GEMM 256x256, 8-phase
#define SA3(tile, u)                                                            \
    do { int s_ = tid*8; int rl_ = s_>>6;                                       \
        int x_ = (s_&63) ^ ((rl_&7)<<3);                                        \
        __builtin_amdgcn_global_load_lds(                                       \
            (gas_t)(A + (size_t)(m0 + (u)*64 + rl_)*K + (size_t)(tile)*64 + x_),\
            (las_t)&lA3[(tile)&1][(u)*4096 + s_], 16, 0, 0);                    \
    } while (0)
#define SB3(tile, v)                                                            \
    do { int s_ = tid*8; int rl_ = s_>>6; int lr_ = (v)*64 + rl_;               \
        int r_ = (lr_ < 128) ? ((lr_&31) + ((lr_>>5)<<6))                       \
                             : (32 + ((lr_-128)&31) + (((lr_-128)>>5)<<6));     \
        int x_ = (s_&63) ^ ((rl_&7)<<3);                                        \
        __builtin_amdgcn_global_load_lds(                                       \
            (gas_t)(BT + (size_t)(n0 + r_)*K + (size_t)(tile)*64 + x_),         \
            (las_t)&lB3[(tile)&1][(v)*4096 + s_], 16, 0, 0);                    \
    } while (0)
#define RDA3(dst, mig, mi, kh) { int lr_ = wm*128 + ((mig)*4+(mi))*16 + r16;    \
    dst = *(const bf16x8*)&lA3[db_][lr_*64 + ((((kh)*32) | kfrag) ^ ((lr_&7)<<3))]; }
#define RDB3(dst, ni, kh) { int lr_ = wn*32 + (((ni)&1)<<4) + r16 + (((ni)>=2)?128:0); \
    dst = *(const bf16x8*)&lB3[db_][lr_*64 + ((((kh)*32) | kfrag) ^ ((lr_&7)<<3))]; }
#define MF3(mb_, nb_)                                                           \
    _Pragma("unroll") for (int kh = 0; kh < 2; kh++)                            \
        _Pragma("unroll") for (int mi = 0; mi < 4; mi++)                        \
            _Pragma("unroll") for (int ni = 0; ni < 2; ni++)                    \
                acc[(mb_)+mi][(nb_)+ni] = __builtin_amdgcn_mfma_f32_16x16x32_bf16( \
                    bfr[(nb_)+ni][kh], afr[mi][kh], acc[(mb_)+mi][(nb_)+ni], 0, 0, 0);

#define QUAD3(nn, cs, sn)                                                       \
    { const int db_ = (nn)&1;                                                   \
      /* P1 */                                                                  \
      _Pragma("unroll") for (int mi=0;mi<4;mi++){RDA3(afr[mi][0],0,mi,0);RDA3(afr[mi][1],0,mi,1);} \
      _Pragma("unroll") for (int ni=0;ni<2;ni++){RDB3(bfr[ni][0],ni,0);RDB3(bfr[ni][1],ni,1);}     \
      BARS;                                                                     \
      __builtin_amdgcn_s_setprio(1); MF3(0,0); __builtin_amdgcn_s_setprio(0);   \
      BARS;                                                                     \
      /* P2 */                                                                  \
      _Pragma("unroll") for (int ni=2;ni<4;ni++){RDB3(bfr[ni][0],ni,0);RDB3(bfr[ni][1],ni,1);}     \
      if (cs) { SA3(sn,0); SA3(sn,2); }                                         \
      BARS;                                                                     \
      __builtin_amdgcn_s_setprio(1); MF3(0,2); __builtin_amdgcn_s_setprio(0);   \
      BARS;                                                                     \
      /* P3 */                                                                  \
      _Pragma("unroll") for (int mi=0;mi<4;mi++){RDA3(afr[mi][0],1,mi,0);RDA3(afr[mi][1],1,mi,1);} \
      if (cs) { SB3(sn,0); SB3(sn,1); SB3(sn,2); SB3(sn,3); }                   \
      BARS;                                                                     \
      __builtin_amdgcn_s_setprio(1); MF3(4,0); __builtin_amdgcn_s_setprio(0);   \
      BARS;                                                                     \
      /* P4 */                                                                  \
      if (cs) { SA3(sn,1); SA3(sn,3); }                                         \
      BARS;                                                                     \
      __builtin_amdgcn_s_setprio(1); MF3(4,2); __builtin_amdgcn_s_setprio(0);   \
      if (cs) asm volatile("s_waitcnt vmcnt(8)" ::: "memory");                  \
      else    asm volatile("s_waitcnt vmcnt(0)" ::: "memory");                  \
      BARS; }

__global__ __launch_bounds__(512, 2) void k_gemm3(
    const bf16* __restrict__ A, const bf16* __restrict__ BT,
    const float* __restrict__ bias, const float* __restrict__ res,
    float* __restrict__ outf, bf16* __restrict__ outb,
    int K, int Nout, int relu, int mswap, int qpre)
{
    __shared__ alignas(16) bf16 lA3[2][256 * 64];
    __shared__ alignas(16) bf16 lB3[2][256 * 64];
    int tid = threadIdx.x;
    int lane = tid & 63, w = tid >> 6;
    int wm = w >> 2, wn = w & 3;           // 2M x 4N waves
    int nb = mswap ? blockIdx.y : blockIdx.x;
    int mb = mswap ? blockIdx.x : blockIdx.y;
    int n0 = nb * 256, m0 = mb * 256;
    int r16 = lane & 15, g4 = lane >> 4;
    int kfrag = g4 * 8;

    f32x4 acc[8][4];
    const f32x4 fzero = {0.f, 0.f, 0.f, 0.f};
    #pragma unroll
    for (int i = 0; i < 8; i++)
        #pragma unroll
        for (int j = 0; j < 4; j++) acc[i][j] = fzero;

    bf16x8 afr[4][2];
    bf16x8 bfr[4][2];

    int nt = K >> 6;
    SA3(0,0); SA3(0,1); SA3(0,2); SA3(0,3);
    SB3(0,0); SB3(0,1); SB3(0,2); SB3(0,3);
    SA3(1,0); SA3(1,1); SA3(1,2); SA3(1,3);
    SB3(1,0); SB3(1,1); SB3(1,2); SB3(1,3);
    asm volatile("s_waitcnt vmcnt(8)" ::: "memory");
    BARS;
    for (int it2 = 0; it2 < nt; it2 += 2) {
        bool c2 = (it2 + 2 < nt), c3 = (it2 + 3 < nt);
        QUAD3(it2,     c2, it2 + 2);
        QUAD3(it2 + 1, c3, it2 + 3);
    }
    GEMM_EPILOGUE(8, 128)
}

// ---------------------------------------------------------------- fallback GEMM (f32 B)
__global__ __launch_bounds__(256) void k_gemm_f32b(
    const bf16* __restrict__ A, const float* __restrict__ Bm,
    const float* __restrict__ bias, float* __restrict__ outf,
    int M, int N, int K)
{
    __shared__ alignas(16) bf16 lA[128][40];
    __shared__ alignas(16) bf16 lB[128][40];
    int tid  = threadIdx.x;
    int lane = tid & 63, wid = tid >> 6;
    int wm = wid >> 1, wn = wid & 1;
    int m0 = blockIdx.x * 128, n0 = blockIdx.y * 128;
    int r16 = lane & 15, g4 = lane >> 4;

    f32x4 acc[4][4];
    const f32x4 fzero = {0.f, 0.f, 0.f, 0.f};
    #pragma unroll
    for (int i = 0; i < 4; i++)
        #pragma unroll
        for (int j = 0; j < 4; j++) acc[i][j] = fzero;

    int arow = tid >> 2, aseg = tid & 3;
    int bkr  = tid >> 3, bnb  = tid & 7;
    bool nfull = (n0 + 128 <= N);

    for (int k0 = 0; k0 < K; k0 += 32) {
        *(uint4*)&lA[arow][aseg*8] =
            *(const uint4*)(A + (size_t)(m0 + arow) * K + k0 + aseg*8);
        *(uint4*)&lA[arow + 64][aseg*8] =
            *(const uint4*)(A + (size_t)(m0 + arow + 64) * K + k0 + aseg*8);
        const float* bsrc = Bm + (size_t)(k0 + bkr) * N + n0;
        #pragma unroll
        for (int q = 0; q < 4; q++) {
            int n = q*32 + bnb*4;
            #pragma unroll
            for (int i = 0; i < 4; i++) {
                float fv = 0.0f;
                if (nfull || (n0 + n + i < N)) fv = bsrc[n + i];
                lB[n+i][bkr] = (bf16)fv;
            }
        }
        __syncthreads();
        int kb = g4 * 8;
        bf16x8 af[4], bfr[4];
        #pragma unroll
        for (int mi = 0; mi < 4; mi++)
            af[mi] = *(const bf16x8*)&lA[wm*64 + mi*16 + r16][kb];
        #pragma unroll
        for (int ni = 0; ni < 4; ni++)
            bfr[ni] = *(const bf16x8*)&lB[wn*64 + ni*16 + r16][kb];
        #pragma unroll
        for (int mi = 0; mi < 4; mi++)
            #pragma unroll
            for (int ni = 0; ni < 4; ni++)
                acc[mi][ni] = __builtin_amdgcn_mfma_f32_16x16x32_bf16(
                    af[mi], bfr[ni], acc[mi][ni], 0, 0, 0);
        __syncthreads();
    }

    #pragma unroll
    for (int ni = 0; ni < 4; ni++) {
        int col = n0 + wn*64 + ni*16 + r16;
        if (col >= N) continue;
        float bi = bias[col];
        #pragma unroll
        for (int mi = 0; mi < 4; mi++) {
            #pragma unroll
            for (int j = 0; j < 4; j++) {
                int row = m0 + wm*64 + mi*16 + g4*4 + j;
                outf[(size_t)row * N + col] = acc[mi][ni][j] + bi;
            }
        }
    }
}

// ---------------------------------------------------------------- attention v4
// LPT-paired causal blocks: grid (TT/256, B*H); block i handles q-tiles i and
// (15-i) -> uniform 17 KV-tiles per block, 256 blocks = 1/CU.
__global__ __launch_bounds__(512) void k_attn4(
    const bf16* __restrict__ qkv, bf16* __restrict__ o)
{
    __shared__ alignas(16) bf16 lK[64][72];    // [s][k] natural, padded
    __shared__ alignas(16) bf16 lVT[64][72];   // [d][s], s-block XOR swizzle
    int tid = threadIdx.x, lane = tid & 63, w = tid >> 6;
    int r16 = lane & 15, g4 = lane >> 4;
    int ib = blockIdx.x;                       // 0..7
    int bh = blockIdx.y, bb = bh >> 4, hh = bh & 15;
    const bf16* base = qkv + (size_t)bb * TT * QS + hh * HDD;
    const bf16* kp = base + 1024;
    const bf16* vp = base + 2048;
    bf16* op = o + (size_t)bb * TT * DD + hh * HDD;

    int krow = tid >> 3, kseg = tid & 7;
    int vsp  = tid >> 4, vseg = tid & 15;
    const f32x4 fzero = {0.f, 0.f, 0.f, 0.f};

    #pragma unroll 1
    for (int pass = 0; pass < 2; pass++) {
        int tb = pass ? (TT/128 - 1 - ib) : ib;
        int t0 = tb * 128;
        int qrow = t0 + w * 16;

        bf16x8 qf0, qf1;
        {
            const bf16* qr = base + (size_t)(qrow + r16) * QS + g4 * 8;
            qf0 = *(const bf16x8*)qr;
            qf1 = *(const bf16x8*)(qr + 32);
        }
        f32x4 oacc[4];
        #pragma unroll
        for (int i = 0; i < 4; i++) oacc[i] = fzero;
        float mrun = -1e30f, lrun = 0.f;

        int send = t0 + 128;
        bf16x8 kr;
        bf16x4 va4, vb4;
        {
            kr  = *(const bf16x8*)(kp + (size_t)krow * QS + kseg * 8);
            va4 = *(const bf16x4*)(vp + (size_t)(2*vsp) * QS + vseg * 4);
            vb4 = *(const bf16x4*)(vp + (size_t)(2*vsp) * QS + QS + vseg * 4);
        }

        for (int s0 = 0; s0 < send; s0 += 64) {
            __syncthreads();   // LDS free (prev compute done)
            *(bf16x8*)&lK[krow][kseg*8] = kr;
            #pragma unroll
            for (int i = 0; i < 4; i++) {
                int d = vseg*4 + i;
                int mpr = (vsp >> 2) ^ (d >> 3);
                bf16x2 pv2 = {va4[i], vb4[i]};
                *(unsigned int*)&lVT[d][mpr*8 + (vsp&3)*2] =
                    __builtin_bit_cast(unsigned int, pv2);
            }
            if (s0 + 64 < send) {
                kr  = *(const bf16x8*)(kp + (size_t)(s0 + 64 + krow) * QS + kseg * 8);
                va4 = *(const bf16x4*)(vp + (size_t)(s0 + 64 + 2*vsp) * QS + vseg * 4);
                vb4 = *(const bf16x4*)(vp + (size_t)(s0 + 64 + 2*vsp) * QS + QS + vseg * 4);
            }
            __syncthreads();   // LDS ready

            if (s0 <= qrow + 15) {
                f32x4 sf[4];
                __builtin_amdgcn_s_setprio(1);
                #pragma unroll
                for (int nf = 0; nf < 4; nf++) {
                    sf[nf] = fzero;
                    bf16x8 kf0 = *(const bf16x8*)&lK[nf*16 + r16][g4*8];
                    bf16x8 kf1 = *(const bf16x8*)&lK[nf*16 + r16][32 + g4*8];
                    sf[nf] = __builtin_amdgcn_mfma_f32_16x16x32_bf16(kf0, qf0, sf[nf], 0, 0, 0);
                    sf[nf] = __builtin_amdgcn_mfma_f32_16x16x32_bf16(kf1, qf1, sf[nf], 0, 0, 0);
                }
                __builtin_amdgcn_s_setprio(0);
                int qa = qrow + r16;
                if (s0 + 63 > qrow) {
                    #pragma unroll
                    for (int nf = 0; nf < 4; nf++)
                        #pragma unroll
                        for (int j = 0; j < 4; j++)
                            if (s0 + nf*16 + g4*4 + j > qa) sf[nf][j] = -1e30f;
                }
                float pm = sf[0][0];
                #pragma unroll
                for (int nf = 0; nf < 4; nf++)
                    #pragma unroll
                    for (int j = 0; j < 4; j++) pm = fmaxf(pm, sf[nf][j]);
                pm = fmaxf(pm, __shfl_xor(pm, 16));
                pm = fmaxf(pm, __shfl_xor(pm, 32));
                bool defer = (__all(pm - mrun <= 8.0f) != 0);
                float al = 1.0f;
                if (!defer) {
                    float mn = fmaxf(mrun, pm);
                    al = __expf(mrun - mn);
                    mrun = mn;
                }
                float ps = 0.f;
                #pragma unroll
                for (int nf = 0; nf < 4; nf++)
                    #pragma unroll
                    for (int j = 0; j < 4; j++) {
                        float p = __expf(sf[nf][j] - mrun);
                        sf[nf][j] = p;
                        ps += p;
                    }
                ps += __shfl_xor(ps, 16);
                ps += __shfl_xor(ps, 32);
                lrun = lrun * al + ps;
                if (!defer) {
                    #pragma unroll
                    for (int nf = 0; nf < 4; nf++)
                        #pragma unroll
                        for (int j = 0; j < 4; j++) oacc[nf][j] *= al;
                }
                unsigned int pk[4][2];
                #pragma unroll
                for (int nf = 0; nf < 4; nf++) {
                    bf16x2 a = {(bf16)sf[nf][0], (bf16)sf[nf][1]};
                    bf16x2 b = {(bf16)sf[nf][2], (bf16)sf[nf][3]};
                    pk[nf][0] = __builtin_bit_cast(unsigned int, a);
                    pk[nf][1] = __builtin_bit_cast(unsigned int, b);
                }
                int srcA = r16 + (2*(g4 & 1))*16;
                int srcB = srcA + 16;
                bool hi2 = (g4 >= 2);
                __builtin_amdgcn_s_setprio(1);
                #pragma unroll
                for (int c = 0; c < 2; c++) {
                    unsigned int a0 = __shfl(pk[2*c  ][0], srcA);
                    unsigned int a1 = __shfl(pk[2*c+1][0], srcA);
                    unsigned int b0 = __shfl(pk[2*c  ][1], srcA);
                    unsigned int b1 = __shfl(pk[2*c+1][1], srcA);
                    unsigned int e0 = __shfl(pk[2*c  ][0], srcB);
                    unsigned int e1 = __shfl(pk[2*c+1][0], srcB);
                    unsigned int f0 = __shfl(pk[2*c  ][1], srcB);
                    unsigned int f1 = __shfl(pk[2*c+1][1], srcB);
                    u32x4 uu = { hi2 ? a1 : a0, hi2 ? b1 : b0,
                                 hi2 ? e1 : e0, hi2 ? f1 : f0 };
                    bf16x8 pf = __builtin_bit_cast(bf16x8, uu);
                    #pragma unroll
                    for (int nf = 0; nf < 4; nf++) {
                        int d = nf*16 + r16;
                        int mread = (4*c + g4) ^ (d >> 3);
                        bf16x8 vt = *(const bf16x8*)&lVT[d][mread*8];
                        oacc[nf] = __builtin_amdgcn_mfma_f32_16x16x32_bf16(
                            vt, pf, oacc[nf], 0, 0, 0);
                    }
                }
                __builtin_amdgcn_s_setprio(0);
            }
        }

        float inv = 1.0f / lrun;
        #pragma unroll
        for (int nf = 0; nf < 4; nf++) {
            f32x4 ov = oacc[nf];
            bf16x4 o4 = {(bf16)(ov[0]*inv), (bf16)(ov[1]*inv),
                         (bf16)(ov[2]*inv), (bf16)(ov[3]*inv)};
            *(bf16x4*)(op + (size_t)(qrow + r16) * DD + nf*16 + g4*4) = o4;
        }
    }
}

// ---------------------------------------------------------------- launcher
extern "C" void kernel_launch(void* const* d_in, const int* in_sizes, int n_in,
                              void* d_out, int out_size, void* d_ws, size_t ws_size,
                              hipStream_t stream)
{
    (void)in_sizes; (void)n_in; (void)out_size;
    const int*   x    = (const int*)  d_in[0];
    const float* tok  = (const float*)d_in[1];
    const float* pos  = (const float*)d_in[2];
    const float* ln1g = (const float*)d_in[3];
    const float* ln1b = (const float*)d_in[4];
    const float* wq   = (const float*)d_in[5];
    const float* bq   = (const float*)d_in[6];
    const float* wk   = (const float*)d_in[7];
    const float* bk   = (const float*)d_in[8];
    const float* wv   = (const float*)d_in[9];
    const float* bv   = (const float*)d_in[10];
    const float* wo   = (const float*)d_in[11];
    const float* bo   = (const float*)d_in[12];
    const float* ln2g = (const float*)d_in[13];
    const float* ln2b = (const float*)d_in[14];
    const float* w1   = (const float*)d_in[15];
    const float* b1   = (const float*)d_in[16];
    const float* w2   = (const float*)d_in[17];
    const float* b2   = (const float*)d_in[18];
    const float* lnfg = (const float*)d_in[19];
    const float* lnfb = (const float*)d_in[20];
    const float* fcw  = (const float*)d_in[21];
    const float* fcb  = (const float*)d_in[22];

    const size_t MB = (size_t)1 << 20;
    char*  sb   = (char*)d_out;
    float* hA   = (float*)(sb);                    // 16 MB  (LN1 f32 out)
    float* hB   = (float*)(sb + 16*MB);            // 16 MB  (embed out / LN2 f32 out)
    bf16*  hnb  = (bf16*) (sb + 32*MB);            //  8 MB  (LN bf16 out, GEMM A)
    bf16*  qkv  = (bf16*) (sb + 40*MB);            // 24 MB  [4096][3072]
    bf16*  obuf = (bf16*) (sb + 64*MB);            //  8 MB  (attn out)
    bf16*  pb   = (bf16*) (sb + 72*MB);            //  8 MB  (proj delta)
    bf16*  f1b  = (bf16*) (sb + 80*MB);            // 32 MB  (FFN hidden)
    bf16*  fout = (bf16*) (sb + 112*MB);           //  8 MB  (FFN2 delta)
    bf16*  WT   = (bf16*) (sb + 120*MB);           // 288 MB packed B^T -> ends 408
    float* bqkv = (float*)(sb + 408*MB);           // 147 KB
    bf16*  hfb  = (bf16*) d_ws;                    //  8 MB  (survives logits write)

    const size_t LWT = 12582912;                   // per-layer WT elems (24 MB)
    const size_t FCWT_BYTES = (size_t)VP * DD * 2; // 103.3 MB
    bool fast_logits = (ws_size >= 8*MB + FCWT_BYTES);
    bf16* fcwT = (bf16*)((char*)d_ws + 8*MB);

    dim3 blk(256);
    dim3 blk512(512);

    // ---- weight prepack (B^T bf16) ----
    k_wtrans<<<dim3(4, 32, 12), blk, 0, stream>>>(wq, WT,               DD, DD, DD, (size_t)DD*DD, LWT);
    k_wtrans<<<dim3(4, 32, 12), blk, 0, stream>>>(wk, WT + 1024*1024,   DD, DD, DD, (size_t)DD*DD, LWT);
    k_wtrans<<<dim3(4, 32, 12), blk, 0, stream>>>(wv, WT + 2048*1024,   DD, DD, DD, (size_t)DD*DD, LWT);
    k_wtrans<<<dim3(4, 32, 12), blk, 0, stream>>>(wo, WT + 3145728,     DD, DD, DD, (size_t)DD*DD, LWT);
    k_wtrans<<<dim3(16, 32, 12), blk, 0, stream>>>(w1, WT + 4194304,    DD, FF, FF, (size_t)DD*FF, LWT);
    k_wtrans<<<dim3(4, 128, 12), blk, 0, stream>>>(w2, WT + 8388608,    FF, DD, DD, (size_t)FF*DD, LWT);
    if (fast_logits)
        k_wtrans<<<dim3(VP/256, 32, 1), blk, 0, stream>>>(fcw, fcwT, DD, VV, VP, 0, 0);
    k_biasmerge<<<dim3(144), blk, 0, stream>>>(bq, bk, bv, bqkv);

    // ---- trunk (residual-add fused into LN) ----
    k_embed<<<MM, blk, 0, stream>>>(x, tok, pos, hB);
    for (int l = 0; l < LL; l++) {
        const bf16* WTl = WT + (size_t)l * LWT;
        k_lnadd<<<MM/4, blk, 0, stream>>>(hB, l ? fout : nullptr,
                                          ln1g + l*DD, ln1b + l*DD, hA, hnb);
        k_gemm2t<128><<<dim3(24, 32), blk, 0, stream>>>(hnb, WTl, bqkv + l*QS,
                                                  nullptr, nullptr, qkv, DD, QS, 0, 0, 1);
        k_attn4<<<dim3(TT/256, BB*HH), blk512, 0, stream>>>(qkv, obuf);
        k_gemm2t<64><<<dim3(8, 64), blk, 0, stream>>>(obuf, WTl + 3145728, bo + l*DD,
                                                 nullptr, nullptr, pb, DD, DD, 0, 0, 0);
        k_lnadd<<<MM/4, blk, 0, stream>>>(hA, pb, ln2g + l*DD, ln2b + l*DD, hB, hnb);
        k_gemm3<<<dim3(FF/256, MM/256), blk512, 0, stream>>>(hnb, WTl + 4194304, b1 + l*FF,
                                                  nullptr, nullptr, f1b, DD, FF, 1, 0, 0);
        k_gemm2t<64><<<dim3(8, 64), blk, 0, stream>>>(f1b, WTl + 8388608, b2 + l*DD,
                                                 nullptr, nullptr, fout, FF, DD, 0, 0, 0);
    }
    k_lnadd<<<MM/4, blk, 0, stream>>>(hB, fout, lnfg, lnfb, nullptr, hfb);

    // ---- logits (m-fastest grid, regular stores) ----
    if (fast_logits) {
        k_gemm3<<<dim3(MM/256, VP/256), blk512, 0, stream>>>(hfb, fcwT, fcb,
                                                      nullptr, (float*)d_out, nullptr,
                                                      DD, VV, 0, 1, 0);
    } else {
        k_gemm_f32b<<<dim3(32, (VV + 127)/128), blk, 0, stream>>>(hfb, fcw, fcb,
                                                                  (float*)d_out, MM, VV, DD);
    }
}

// Round 17
// 3992.248 us; speedup vs baseline: 1.0391x; 1.0132x over previous
//
#include <hip/hip_runtime.h>

#define BB 2
#define TT 2048
#define DD 1024
#define HH 16
#define LL 12
#define VV 50257
#define VP 50432            // V padded to multiple of 256
#define HDD 64
#define FF 4096
#define MM (BB*TT)          // 4096 rows
#define QS 3072             // fused qkv row stride

typedef __bf16 bf16;
typedef __bf16 bf16x8 __attribute__((ext_vector_type(8)));
typedef __bf16 bf16x4 __attribute__((ext_vector_type(4)));
typedef __bf16 bf16x2 __attribute__((ext_vector_type(2)));
typedef float  f32x4  __attribute__((ext_vector_type(4)));
typedef float  f32x4u __attribute__((ext_vector_type(4), aligned(4)));
typedef unsigned int u32x4 __attribute__((ext_vector_type(4)));

typedef const __attribute__((address_space(1))) void* gas_t;
typedef __attribute__((address_space(3))) void* las_t;

// ---------------------------------------------------------------- embedding
__global__ __launch_bounds__(256) void k_embed(const int* __restrict__ x,
    const float* __restrict__ tok, const float* __restrict__ pos,
    float* __restrict__ h)
{
    int row = blockIdx.x;
    int t   = row & (TT - 1);
    int idx = x[row];
    int c   = threadIdx.x * 4;
    float4 a = *(const float4*)(tok + (size_t)idx * DD + c);
    float4 p = *(const float4*)(pos + (size_t)t   * DD + c);
    a.x += p.x; a.y += p.y; a.z += p.z; a.w += p.w;
    *(float4*)(h + (size_t)row * DD + c) = a;
}

// ---------------------------------------------------------------- residual-add layernorm
// Wave-per-row: 4 rows/block, 64 lanes/row, 16 elems/lane. No LDS, no barriers.
__global__ __launch_bounds__(256) void k_lnadd(const float* __restrict__ resf,
    const bf16* __restrict__ delta,
    const float* __restrict__ g, const float* __restrict__ b,
    float* __restrict__ outf, bf16* __restrict__ outb)
{
    int tid = threadIdx.x, lane = tid & 63, wid = tid >> 6;
    int row = blockIdx.x * 4 + wid;
    const float* rp = resf + (size_t)row * DD;

    float4 v[4];
    #pragma unroll
    for (int k = 0; k < 4; k++) {
        int c = k * 256 + lane * 4;
        v[k] = *(const float4*)(rp + c);
        if (delta) {
            bf16x4 d4 = *(const bf16x4*)(delta + (size_t)row * DD + c);
            v[k].x += (float)d4[0]; v[k].y += (float)d4[1];
            v[k].z += (float)d4[2]; v[k].w += (float)d4[3];
        }
    }
    float s = 0.f, s2 = 0.f;
    #pragma unroll
    for (int k = 0; k < 4; k++) {
        s  += v[k].x + v[k].y + v[k].z + v[k].w;
        s2 += v[k].x*v[k].x + v[k].y*v[k].y + v[k].z*v[k].z + v[k].w*v[k].w;
    }
    #pragma unroll
    for (int d = 1; d < 64; d <<= 1) { s += __shfl_xor(s, d); s2 += __shfl_xor(s2, d); }
    float mean = s * (1.0f / DD);
    float var  = s2 * (1.0f / DD) - mean * mean;
    float inv  = 1.0f / sqrtf(var + 1e-5f);

    #pragma unroll
    for (int k = 0; k < 4; k++) {
        int c = k * 256 + lane * 4;
        float4 gg = *(const float4*)(g + c);
        float4 bb = *(const float4*)(b + c);
        float o0 = (v[k].x - mean) * inv * gg.x + bb.x;
        float o1 = (v[k].y - mean) * inv * gg.y + bb.y;
        float o2 = (v[k].z - mean) * inv * gg.z + bb.z;
        float o3 = (v[k].w - mean) * inv * gg.w + bb.w;
        size_t o = (size_t)row * DD + c;
        if (outf) { float4 r = {o0, o1, o2, o3}; *(float4*)(outf + o) = r; }
        if (outb) {
            bf16x4 r4 = {(bf16)o0, (bf16)o1, (bf16)o2, (bf16)o3};
            *(bf16x4*)(outb + o) = r4;
        }
    }
}

// ---------------------------------------------------------------- weight transpose+convert
__global__ __launch_bounds__(256) void k_wtrans(
    const float* __restrict__ src, bf16* __restrict__ dst,
    int K, int N, int Npad, size_t srcLS, size_t dstLS)
{
    src += (size_t)blockIdx.z * srcLS;
    dst += (size_t)blockIdx.z * dstLS;
    int k0 = blockIdx.y * 32, n0 = blockIdx.x * 256;
    __shared__ float tile[32][256];
    int tid = threadIdx.x;
    #pragma unroll
    for (int p = 0; p < 8; p++) {
        int kk = p * 4 + (tid >> 6);
        int nn = (tid & 63) * 4;
        const float* sp = src + (size_t)(k0 + kk) * N + n0 + nn;
        f32x4u v = {0.f, 0.f, 0.f, 0.f};
        if (n0 + nn + 3 < N) {
            v = *(const f32x4u*)sp;            // dwordx4, 4B-align OK
        } else {
            #pragma unroll
            for (int i = 0; i < 4; i++)
                if (n0 + nn + i < N) v[i] = sp[i];
        }
        *(f32x4*)&tile[kk][nn] = v;
    }
    __syncthreads();
    int n = n0 + tid;
    if (n < Npad) {
        bf16 rowv[32];
        #pragma unroll
        for (int kk = 0; kk < 32; kk++) rowv[kk] = (bf16)tile[kk][tid];
        bf16* dp = dst + (size_t)n * K + k0;
        #pragma unroll
        for (int s = 0; s < 4; s++)
            *(bf16x8*)(dp + s * 8) = *(const bf16x8*)&rowv[s * 8];
    }
}

// ---------------------------------------------------------------- bias merge (q|k|v)
__global__ __launch_bounds__(256) void k_biasmerge(
    const float* __restrict__ bq, const float* __restrict__ bk,
    const float* __restrict__ bv, float* __restrict__ dst)
{
    int i = blockIdx.x * 256 + threadIdx.x;
    if (i >= LL * QS) return;
    int l = i / QS, j = i % QS;
    float v = (j < 1024) ? bq[l*1024 + j]
            : (j < 2048) ? bk[l*1024 + j - 1024]
                         : bv[l*1024 + j - 2048];
    dst[i] = v;
}

// ================================================================ GEMM epilogue (shared)
#define GEMM_EPILOGUE(MI_CNT, WM_STRIDE)                                        \
    bool nalign = ((Nout & 3) == 0);                                            \
    _Pragma("unroll")                                                           \
    for (int mi = 0; mi < MI_CNT; mi++) {                                       \
        int row = m0 + wm*WM_STRIDE + mi*16 + r16;                              \
        _Pragma("unroll")                                                       \
        for (int ni = 0; ni < 4; ni++) {                                        \
            int col0 = n0 + wn*64 + ni*16 + g4*4;                               \
            f32x4 v = acc[mi][ni];                                              \
            float sc = (qpre && col0 < 1024) ? 0.125f : 1.0f;                   \
            if (col0 + 3 < Nout) {                                              \
                if (bias) {                                                     \
                    float4 bi = *(const float4*)(bias + col0);                  \
                    v[0] += bi.x; v[1] += bi.y; v[2] += bi.z; v[3] += bi.w;     \
                }                                                               \
                if (res) {                                                      \
                    float4 rr = *(const float4*)(res + (size_t)row*Nout + col0);\
                    v[0] += rr.x; v[1] += rr.y; v[2] += rr.z; v[3] += rr.w;     \
                }                                                               \
                if (relu) { _Pragma("unroll")                                   \
                    for (int j = 0; j < 4; j++) v[j] = fmaxf(v[j], 0.0f); }     \
                if (outf) {                                                     \
                    float* p = outf + (size_t)row * Nout + col0;                \
                    if (nalign) *(f32x4*)p = v; else *(f32x4u*)p = v;           \
                }                                                               \
                if (outb) {                                                     \
                    bf16x4 o4 = {(bf16)(v[0]*sc), (bf16)(v[1]*sc),              \
                                 (bf16)(v[2]*sc), (bf16)(v[3]*sc)};             \
                    *(bf16x4*)(outb + (size_t)row * Nout + col0) = o4;          \
                }                                                               \
            } else {                                                            \
                _Pragma("unroll")                                               \
                for (int j = 0; j < 4; j++) {                                   \
                    int col = col0 + j;                                         \
                    if (col >= Nout) continue;                                  \
                    float vv = v[j] + (bias ? bias[col] : 0.0f);                \
                    if (res)  vv += res[(size_t)row * Nout + col];              \
                    if (relu) vv = fmaxf(vv, 0.0f);                             \
                    if (outf) outf[(size_t)row * Nout + col] = vv;              \
                    if (outb) outb[(size_t)row * Nout + col] = (bf16)(vv*sc);   \
                }                                                               \
            }                                                                   \
        }                                                                       \
    }

#define BARS { __builtin_amdgcn_sched_barrier(0); __builtin_amdgcn_s_barrier(); }

// ---------------------------------------------------------------- GEMM MTx128 (4-phase)
#define STG2(nn, kk)                                                            \
    do { const int k0_ = (nn)*64 + (kk)*32; const int db_ = (nn)&1;             \
        _Pragma("unroll") for (int i_ = 0; i_ < AL; i_++) {                     \
            int a_ = i_*2048 + tid*8;                                           \
            int sr_ = a_>>6, x_ = (a_&63) ^ ((sr_&7)<<3);                       \
            int r_ = 2*sr_ + (x_>>5), e_ = x_&31;                               \
            __builtin_amdgcn_global_load_lds(                                   \
                (gas_t)(A + (size_t)(m0+r_)*K + k0_+e_),                        \
                (las_t)&lA[db_][kk][a_], 16, 0, 0);                             \
        }                                                                       \
        _Pragma("unroll") for (int i_ = 0; i_ < 2; i_++) {                      \
            int a_ = i_*2048 + tid*8;                                           \
            int sr_ = a_>>6, x_ = (a_&63) ^ ((sr_&7)<<3);                       \
            int r_ = 2*sr_ + (x_>>5), e_ = x_&31;                               \
            __builtin_amdgcn_global_load_lds(                                   \
                (gas_t)(BT + (size_t)(n0+r_)*K + k0_+e_),                       \
                (las_t)&lB[db_][kk][a_], 16, 0, 0);                             \
        }                                                                       \
    } while (0)

#define WAITG                                                                   \
    { if constexpr (MT == 128) asm volatile("s_waitcnt vmcnt(4)" ::: "memory"); \
      else                     asm volatile("s_waitcnt vmcnt(3)" ::: "memory"); }

#define PH2(nn, kk, sn, sk, wv)                                                 \
    { const int db_ = (nn)&1;                                                   \
        bf16x8 af[MI], bfr[4];                                                  \
        _Pragma("unroll") for (int mi = 0; mi < MI; mi++) {                     \
            int row_ = wm*(MT/2) + mi*16 + r16;                                 \
            int sr_ = row_>>1;                                                  \
            int xp_ = (((row_&1)<<5) | kfrag) ^ ((sr_&7)<<3);                   \
            af[mi] = *(const bf16x8*)&lA[db_][kk][sr_*64 + xp_];                \
        }                                                                       \
        _Pragma("unroll") for (int ni = 0; ni < 4; ni++) {                      \
            int row_ = wn*64 + ni*16 + r16;                                     \
            int sr_ = row_>>1;                                                  \
            int xp_ = (((row_&1)<<5) | kfrag) ^ ((sr_&7)<<3);                   \
            bfr[ni] = *(const bf16x8*)&lB[db_][kk][sr_*64 + xp_];               \
        }                                                                       \
        bool st_ = (sn) < nt;                                                   \
        if (st_) STG2(sn, sk);                                                  \
        BARS;                                                                   \
        __builtin_amdgcn_s_setprio(1);                                          \
        _Pragma("unroll") for (int mi = 0; mi < MI; mi++)                       \
            _Pragma("unroll") for (int ni = 0; ni < 4; ni++)                    \
                acc[mi][ni] = __builtin_amdgcn_mfma_f32_16x16x32_bf16(          \
                    bfr[ni], af[mi], acc[mi][ni], 0, 0, 0);                     \
        __builtin_amdgcn_s_setprio(0);                                          \
        if (wv) { if (st_) WAITG                                                \
                  else     asm volatile("s_waitcnt vmcnt(0)" ::: "memory"); }   \
        BARS;                                                                   \
    }

template<int MT>
__global__ __launch_bounds__(256) void k_gemm2t(
    const bf16* __restrict__ A, const bf16* __restrict__ BT,
    const float* __restrict__ bias, const float* __restrict__ res,
    float* __restrict__ outf, bf16* __restrict__ outb,
    int K, int Nout, int relu, int mswap, int qpre)
{
    constexpr int AL = MT / 64;        // A loads per stage group
    constexpr int MI = MT / 32;        // mi fragments per wave
    __shared__ alignas(16) bf16 lA[2][2][MT * 32];
    __shared__ alignas(16) bf16 lB[2][2][128 * 32];
    int tid = threadIdx.x;
    int lane = tid & 63, w = tid >> 6;
    int wm = w >> 1, wn = w & 1;
    int nb = mswap ? blockIdx.y : blockIdx.x;
    int mb = mswap ? blockIdx.x : blockIdx.y;
    int n0 = nb * 128, m0 = mb * MT;
    int r16 = lane & 15, g4 = lane >> 4;
    int kfrag = g4 * 8;

    f32x4 acc[MI][4];
    const f32x4 fzero = {0.f, 0.f, 0.f, 0.f};
    #pragma unroll
    for (int i = 0; i < MI; i++)
        #pragma unroll
        for (int j = 0; j < 4; j++) acc[i][j] = fzero;

    int nt = K >> 6;
    STG2(0, 0); STG2(0, 1); STG2(1, 0);
    WAITG
    BARS;
    for (int it2 = 0; it2 < nt; it2 += 2) {
        PH2(it2,     0, it2 + 1, 1, 0);
        PH2(it2,     1, it2 + 2, 0, 1);
        PH2(it2 + 1, 0, it2 + 2, 1, 0);
        PH2(it2 + 1, 1, it2 + 3, 0, 1);
    }
    GEMM_EPILOGUE(MI, (MT/2))
}

// ================================================================ GEMM 256x256, 8-phase
#define SA3(tile, u)                                                            \
    do { int s_ = tid*8; int rl_ = s_>>6;                                       \
        int x_ = (s_&63) ^ ((rl_&7)<<3);                                        \
        __builtin_amdgcn_global_load_lds(                                       \
            (gas_t)(A + (size_t)(m0 + (u)*64 + rl_)*K + (size_t)(tile)*64 + x_),\
            (las_t)&lA3[(tile)&1][(u)*4096 + s_], 16, 0, 0);                    \
    } while (0)
#define SB3(tile, v)                                                            \
    do { int s_ = tid*8; int rl_ = s_>>6; int lr_ = (v)*64 + rl_;               \
        int r_ = (lr_ < 128) ? ((lr_&31) + ((lr_>>5)<<6))                       \
                             : (32 + ((lr_-128)&31) + (((lr_-128)>>5)<<6));     \
        int x_ = (s_&63) ^ ((rl_&7)<<3);                                        \
        __builtin_amdgcn_global_load_lds(                                       \
            (gas_t)(BT + (size_t)(n0 + r_)*K + (size_t)(tile)*64 + x_),         \
            (las_t)&lB3[(tile)&1][(v)*4096 + s_], 16, 0, 0);                    \
    } while (0)
#define RDA3(dst, mig, mi, kh) { int lr_ = wm*128 + ((mig)*4+(mi))*16 + r16;    \
    dst = *(const bf16x8*)&lA3[db_][lr_*64 + ((((kh)*32) | kfrag) ^ ((lr_&7)<<3))]; }
#define RDB3(dst, ni, kh) { int lr_ = wn*32 + (((ni)&1)<<4) + r16 + (((ni)>=2)?128:0); \
    dst = *(const bf16x8*)&lB3[db_][lr_*64 + ((((kh)*32) | kfrag) ^ ((lr_&7)<<3))]; }
#define MF3(mb_, nb_)                                                           \
    _Pragma("unroll") for (int kh = 0; kh < 2; kh++)                            \
        _Pragma("unroll") for (int mi = 0; mi < 4; mi++)                        \
            _Pragma("unroll") for (int ni = 0; ni < 2; ni++)                    \
                acc[(mb_)+mi][(nb_)+ni] = __builtin_amdgcn_mfma_f32_16x16x32_bf16( \
                    bfr[(nb_)+ni][kh], afr[mi][kh], acc[(mb_)+mi][(nb_)+ni], 0, 0, 0);

#define QUAD3(nn, cs, sn)                                                       \
    { const int db_ = (nn)&1;                                                   \
      /* P1 */                                                                  \
      _Pragma("unroll") for (int mi=0;mi<4;mi++){RDA3(afr[mi][0],0,mi,0);RDA3(afr[mi][1],0,mi,1);} \
      _Pragma("unroll") for (int ni=0;ni<2;ni++){RDB3(bfr[ni][0],ni,0);RDB3(bfr[ni][1],ni,1);}     \
      BARS;                                                                     \
      __builtin_amdgcn_s_setprio(1); MF3(0,0); __builtin_amdgcn_s_setprio(0);   \
      BARS;                                                                     \
      /* P2 */                                                                  \
      _Pragma("unroll") for (int ni=2;ni<4;ni++){RDB3(bfr[ni][0],ni,0);RDB3(bfr[ni][1],ni,1);}     \
      if (cs) { SA3(sn,0); SA3(sn,2); }                                         \
      BARS;                                                                     \
      __builtin_amdgcn_s_setprio(1); MF3(0,2); __builtin_amdgcn_s_setprio(0);   \
      BARS;                                                                     \
      /* P3 */                                                                  \
      _Pragma("unroll") for (int mi=0;mi<4;mi++){RDA3(afr[mi][0],1,mi,0);RDA3(afr[mi][1],1,mi,1);} \
      if (cs) { SB3(sn,0); SB3(sn,1); SB3(sn,2); SB3(sn,3); }                   \
      BARS;                                                                     \
      __builtin_amdgcn_s_setprio(1); MF3(4,0); __builtin_amdgcn_s_setprio(0);   \
      BARS;                                                                     \
      /* P4 */                                                                  \
      if (cs) { SA3(sn,1); SA3(sn,3); }                                         \
      BARS;                                                                     \
      __builtin_amdgcn_s_setprio(1); MF3(4,2); __builtin_amdgcn_s_setprio(0);   \
      if (cs) asm volatile("s_waitcnt vmcnt(8)" ::: "memory");                  \
      else    asm volatile("s_waitcnt vmcnt(0)" ::: "memory");                  \
      BARS; }

__global__ __launch_bounds__(512, 2) void k_gemm3(
    const bf16* __restrict__ A, const bf16* __restrict__ BT,
    const float* __restrict__ bias, const float* __restrict__ res,
    float* __restrict__ outf, bf16* __restrict__ outb,
    int K, int Nout, int relu, int mswap, int qpre)
{
    __shared__ alignas(16) bf16 lA3[2][256 * 64];
    __shared__ alignas(16) bf16 lB3[2][256 * 64];
    int tid = threadIdx.x;
    int lane = tid & 63, w = tid >> 6;
    int wm = w >> 2, wn = w & 3;           // 2M x 4N waves
    int nb = mswap ? blockIdx.y : blockIdx.x;
    int mb = mswap ? blockIdx.x : blockIdx.y;
    int n0 = nb * 256, m0 = mb * 256;
    int r16 = lane & 15, g4 = lane >> 4;
    int kfrag = g4 * 8;

    f32x4 acc[8][4];
    const f32x4 fzero = {0.f, 0.f, 0.f, 0.f};
    #pragma unroll
    for (int i = 0; i < 8; i++)
        #pragma unroll
        for (int j = 0; j < 4; j++) acc[i][j] = fzero;

    bf16x8 afr[4][2];
    bf16x8 bfr[4][2];

    int nt = K >> 6;
    SA3(0,0); SA3(0,1); SA3(0,2); SA3(0,3);
    SB3(0,0); SB3(0,1); SB3(0,2); SB3(0,3);
    SA3(1,0); SA3(1,1); SA3(1,2); SA3(1,3);
    SB3(1,0); SB3(1,1); SB3(1,2); SB3(1,3);
    asm volatile("s_waitcnt vmcnt(8)" ::: "memory");
    BARS;
    for (int it2 = 0; it2 < nt; it2 += 2) {
        bool c2 = (it2 + 2 < nt), c3 = (it2 + 3 < nt);
        QUAD3(it2,     c2, it2 + 2);
        QUAD3(it2 + 1, c3, it2 + 3);
    }
    GEMM_EPILOGUE(8, 128)
}

// ---------------------------------------------------------------- fallback GEMM (f32 B)
__global__ __launch_bounds__(256) void k_gemm_f32b(
    const bf16* __restrict__ A, const float* __restrict__ Bm,
    const float* __restrict__ bias, float* __restrict__ outf,
    int M, int N, int K)
{
    __shared__ alignas(16) bf16 lA[128][40];
    __shared__ alignas(16) bf16 lB[128][40];
    int tid  = threadIdx.x;
    int lane = tid & 63, wid = tid >> 6;
    int wm = wid >> 1, wn = wid & 1;
    int m0 = blockIdx.x * 128, n0 = blockIdx.y * 128;
    int r16 = lane & 15, g4 = lane >> 4;

    f32x4 acc[4][4];
    const f32x4 fzero = {0.f, 0.f, 0.f, 0.f};
    #pragma unroll
    for (int i = 0; i < 4; i++)
        #pragma unroll
        for (int j = 0; j < 4; j++) acc[i][j] = fzero;

    int arow = tid >> 2, aseg = tid & 3;
    int bkr  = tid >> 3, bnb  = tid & 7;
    bool nfull = (n0 + 128 <= N);

    for (int k0 = 0; k0 < K; k0 += 32) {
        *(uint4*)&lA[arow][aseg*8] =
            *(const uint4*)(A + (size_t)(m0 + arow) * K + k0 + aseg*8);
        *(uint4*)&lA[arow + 64][aseg*8] =
            *(const uint4*)(A + (size_t)(m0 + arow + 64) * K + k0 + aseg*8);
        const float* bsrc = Bm + (size_t)(k0 + bkr) * N + n0;
        #pragma unroll
        for (int q = 0; q < 4; q++) {
            int n = q*32 + bnb*4;
            #pragma unroll
            for (int i = 0; i < 4; i++) {
                float fv = 0.0f;
                if (nfull || (n0 + n + i < N)) fv = bsrc[n + i];
                lB[n+i][bkr] = (bf16)fv;
            }
        }
        __syncthreads();
        int kb = g4 * 8;
        bf16x8 af[4], bfr[4];
        #pragma unroll
        for (int mi = 0; mi < 4; mi++)
            af[mi] = *(const bf16x8*)&lA[wm*64 + mi*16 + r16][kb];
        #pragma unroll
        for (int ni = 0; ni < 4; ni++)
            bfr[ni] = *(const bf16x8*)&lB[wn*64 + ni*16 + r16][kb];
        #pragma unroll
        for (int mi = 0; mi < 4; mi++)
            #pragma unroll
            for (int ni = 0; ni < 4; ni++)
                acc[mi][ni] = __builtin_amdgcn_mfma_f32_16x16x32_bf16(
                    af[mi], bfr[ni], acc[mi][ni], 0, 0, 0);
        __syncthreads();
    }

    #pragma unroll
    for (int ni = 0; ni < 4; ni++) {
        int col = n0 + wn*64 + ni*16 + r16;
        if (col >= N) continue;
        float bi = bias[col];
        #pragma unroll
        for (int mi = 0; mi < 4; mi++) {
            #pragma unroll
            for (int j = 0; j < 4; j++) {
                int row = m0 + wm*64 + mi*16 + g4*4 + j;
                outf[(size_t)row * N + col] = acc[mi][ni][j] + bi;
            }
        }
    }
}

// ---------------------------------------------------------------- attention v4
// LPT-paired causal blocks: grid (TT/256, B*H); block i handles q-tiles i and
// (15-i) -> uniform 17 KV-tiles per block, 256 blocks = 1/CU.
__global__ __launch_bounds__(512) void k_attn4(
    const bf16* __restrict__ qkv, bf16* __restrict__ o)
{
    __shared__ alignas(16) bf16 lK[64][72];    // [s][k] natural, padded
    __shared__ alignas(16) bf16 lVT[64][72];   // [d][s], s-block XOR swizzle
    int tid = threadIdx.x, lane = tid & 63, w = tid >> 6;
    int r16 = lane & 15, g4 = lane >> 4;
    int ib = blockIdx.x;                       // 0..7
    int bh = blockIdx.y, bb = bh >> 4, hh = bh & 15;
    const bf16* base = qkv + (size_t)bb * TT * QS + hh * HDD;
    const bf16* kp = base + 1024;
    const bf16* vp = base + 2048;
    bf16* op = o + (size_t)bb * TT * DD + hh * HDD;

    int krow = tid >> 3, kseg = tid & 7;
    int vsp  = tid >> 4, vseg = tid & 15;
    const f32x4 fzero = {0.f, 0.f, 0.f, 0.f};

    #pragma unroll 1
    for (int pass = 0; pass < 2; pass++) {
        int tb = pass ? (TT/128 - 1 - ib) : ib;
        int t0 = tb * 128;
        int qrow = t0 + w * 16;

        bf16x8 qf0, qf1;
        {
            const bf16* qr = base + (size_t)(qrow + r16) * QS + g4 * 8;
            qf0 = *(const bf16x8*)qr;
            qf1 = *(const bf16x8*)(qr + 32);
        }
        f32x4 oacc[4];
        #pragma unroll
        for (int i = 0; i < 4; i++) oacc[i] = fzero;
        float mrun = -1e30f, lrun = 0.f;

        int send = t0 + 128;
        bf16x8 kr;
        bf16x4 va4, vb4;
        {
            kr  = *(const bf16x8*)(kp + (size_t)krow * QS + kseg * 8);
            va4 = *(const bf16x4*)(vp + (size_t)(2*vsp) * QS + vseg * 4);
            vb4 = *(const bf16x4*)(vp + (size_t)(2*vsp) * QS + QS + vseg * 4);
        }

        for (int s0 = 0; s0 < send; s0 += 64) {
            __syncthreads();   // LDS free (prev compute done)
            *(bf16x8*)&lK[krow][kseg*8] = kr;
            #pragma unroll
            for (int i = 0; i < 4; i++) {
                int d = vseg*4 + i;
                int mpr = (vsp >> 2) ^ (d >> 3);
                bf16x2 pv2 = {va4[i], vb4[i]};
                *(unsigned int*)&lVT[d][mpr*8 + (vsp&3)*2] =
                    __builtin_bit_cast(unsigned int, pv2);
            }
            if (s0 + 64 < send) {
                kr  = *(const bf16x8*)(kp + (size_t)(s0 + 64 + krow) * QS + kseg * 8);
                va4 = *(const bf16x4*)(vp + (size_t)(s0 + 64 + 2*vsp) * QS + vseg * 4);
                vb4 = *(const bf16x4*)(vp + (size_t)(s0 + 64 + 2*vsp) * QS + QS + vseg * 4);
            }
            __syncthreads();   // LDS ready

            if (s0 <= qrow + 15) {
                f32x4 sf[4];
                __builtin_amdgcn_s_setprio(1);
                #pragma unroll
                for (int nf = 0; nf < 4; nf++) {
                    sf[nf] = fzero;
                    bf16x8 kf0 = *(const bf16x8*)&lK[nf*16 + r16][g4*8];
                    bf16x8 kf1 = *(const bf16x8*)&lK[nf*16 + r16][32 + g4*8];
                    sf[nf] = __builtin_amdgcn_mfma_f32_16x16x32_bf16(kf0, qf0, sf[nf], 0, 0, 0);
                    sf[nf] = __builtin_amdgcn_mfma_f32_16x16x32_bf16(kf1, qf1, sf[nf], 0, 0, 0);
                }
                __builtin_amdgcn_s_setprio(0);
                int qa = qrow + r16;
                if (s0 + 63 > qrow) {
                    #pragma unroll
                    for (int nf = 0; nf < 4; nf++)
                        #pragma unroll
                        for (int j = 0; j < 4; j++)
                            if (s0 + nf*16 + g4*4 + j > qa) sf[nf][j] = -1e30f;
                }
                float pm = sf[0][0];
                #pragma unroll
                for (int nf = 0; nf < 4; nf++)
                    #pragma unroll
                    for (int j = 0; j < 4; j++) pm = fmaxf(pm, sf[nf][j]);
                pm = fmaxf(pm, __shfl_xor(pm, 16));
                pm = fmaxf(pm, __shfl_xor(pm, 32));
                bool defer = (__all(pm - mrun <= 8.0f) != 0);
                float al = 1.0f;
                if (!defer) {
                    float mn = fmaxf(mrun, pm);
                    al = __expf(mrun - mn);
                    mrun = mn;
                }
                float ps = 0.f;
                #pragma unroll
                for (int nf = 0; nf < 4; nf++)
                    #pragma unroll
                    for (int j = 0; j < 4; j++) {
                        float p = __expf(sf[nf][j] - mrun);
                        sf[nf][j] = p;
                        ps += p;
                    }
                ps += __shfl_xor(ps, 16);
                ps += __shfl_xor(ps, 32);
                lrun = lrun * al + ps;
                if (!defer) {
                    #pragma unroll
                    for (int nf = 0; nf < 4; nf++)
                        #pragma unroll
                        for (int j = 0; j < 4; j++) oacc[nf][j] *= al;
                }
                unsigned int pk[4][2];
                #pragma unroll
                for (int nf = 0; nf < 4; nf++) {
                    bf16x2 a = {(bf16)sf[nf][0], (bf16)sf[nf][1]};
                    bf16x2 b = {(bf16)sf[nf][2], (bf16)sf[nf][3]};
                    pk[nf][0] = __builtin_bit_cast(unsigned int, a);
                    pk[nf][1] = __builtin_bit_cast(unsigned int, b);
                }
                int srcA = r16 + (2*(g4 & 1))*16;
                int srcB = srcA + 16;
                bool hi2 = (g4 >= 2);
                __builtin_amdgcn_s_setprio(1);
                #pragma unroll
                for (int c = 0; c < 2; c++) {
                    unsigned int a0 = __shfl(pk[2*c  ][0], srcA);
                    unsigned int a1 = __shfl(pk[2*c+1][0], srcA);
                    unsigned int b0 = __shfl(pk[2*c  ][1], srcA);
                    unsigned int b1 = __shfl(pk[2*c+1][1], srcA);
                    unsigned int e0 = __shfl(pk[2*c  ][0], srcB);
                    unsigned int e1 = __shfl(pk[2*c+1][0], srcB);
                    unsigned int f0 = __shfl(pk[2*c  ][1], srcB);
                    unsigned int f1 = __shfl(pk[2*c+1][1], srcB);
                    u32x4 uu = { hi2 ? a1 : a0, hi2 ? b1 : b0,
                                 hi2 ? e1 : e0, hi2 ? f1 : f0 };
                    bf16x8 pf = __builtin_bit_cast(bf16x8, uu);
                    #pragma unroll
                    for (int nf = 0; nf < 4; nf++) {
                        int d = nf*16 + r16;
                        int mread = (4*c + g4) ^ (d >> 3);
                        bf16x8 vt = *(const bf16x8*)&lVT[d][mread*8];
                        oacc[nf] = __builtin_amdgcn_mfma_f32_16x16x32_bf16(
                            vt, pf, oacc[nf], 0, 0, 0);
                    }
                }
                __builtin_amdgcn_s_setprio(0);
            }
        }

        float inv = 1.0f / lrun;
        #pragma unroll
        for (int nf = 0; nf < 4; nf++) {
            f32x4 ov = oacc[nf];
            bf16x4 o4 = {(bf16)(ov[0]*inv), (bf16)(ov[1]*inv),
                         (bf16)(ov[2]*inv), (bf16)(ov[3]*inv)};
            *(bf16x4*)(op + (size_t)(qrow + r16) * DD + nf*16 + g4*4) = o4;
        }
    }
}

// ---------------------------------------------------------------- launcher
extern "C" void kernel_launch(void* const* d_in, const int* in_sizes, int n_in,
                              void* d_out, int out_size, void* d_ws, size_t ws_size,
                              hipStream_t stream)
{
    (void)in_sizes; (void)n_in; (void)out_size;
    const int*   x    = (const int*)  d_in[0];
    const float* tok  = (const float*)d_in[1];
    const float* pos  = (const float*)d_in[2];
    const float* ln1g = (const float*)d_in[3];
    const float* ln1b = (const float*)d_in[4];
    const float* wq   = (const float*)d_in[5];
    const float* bq   = (const float*)d_in[6];
    const float* wk   = (const float*)d_in[7];
    const float* bk   = (const float*)d_in[8];
    const float* wv   = (const float*)d_in[9];
    const float* bv   = (const float*)d_in[10];
    const float* wo   = (const float*)d_in[11];
    const float* bo   = (const float*)d_in[12];
    const float* ln2g = (const float*)d_in[13];
    const float* ln2b = (const float*)d_in[14];
    const float* w1   = (const float*)d_in[15];
    const float* b1   = (const float*)d_in[16];
    const float* w2   = (const float*)d_in[17];
    const float* b2   = (const float*)d_in[18];
    const float* lnfg = (const float*)d_in[19];
    const float* lnfb = (const float*)d_in[20];
    const float* fcw  = (const float*)d_in[21];
    const float* fcb  = (const float*)d_in[22];

    const size_t MB = (size_t)1 << 20;
    char*  sb   = (char*)d_out;
    float* hA   = (float*)(sb);                    // 16 MB  (LN1 f32 out)
    float* hB   = (float*)(sb + 16*MB);            // 16 MB  (embed out / LN2 f32 out)
    bf16*  hnb  = (bf16*) (sb + 32*MB);            //  8 MB  (LN bf16 out, GEMM A)
    bf16*  qkv  = (bf16*) (sb + 40*MB);            // 24 MB  [4096][3072]
    bf16*  obuf = (bf16*) (sb + 64*MB);            //  8 MB  (attn out)
    bf16*  pb   = (bf16*) (sb + 72*MB);            //  8 MB  (proj delta)
    bf16*  f1b  = (bf16*) (sb + 80*MB);            // 32 MB  (FFN hidden)
    bf16*  fout = (bf16*) (sb + 112*MB);           //  8 MB  (FFN2 delta)
    bf16*  WT   = (bf16*) (sb + 120*MB);           // 288 MB packed B^T -> ends 408
    float* bqkv = (float*)(sb + 408*MB);           // 147 KB
    bf16*  hfb  = (bf16*) d_ws;                    //  8 MB  (survives logits write)

    const size_t LWT = 12582912;                   // per-layer WT elems (24 MB)
    const size_t FCWT_BYTES = (size_t)VP * DD * 2; // 103.3 MB
    bool fast_logits = (ws_size >= 8*MB + FCWT_BYTES);
    bf16* fcwT = (bf16*)((char*)d_ws + 8*MB);

    dim3 blk(256);
    dim3 blk512(512);

    // ---- weight prepack (B^T bf16) ----
    k_wtrans<<<dim3(4, 32, 12), blk, 0, stream>>>(wq, WT,               DD, DD, DD, (size_t)DD*DD, LWT);
    k_wtrans<<<dim3(4, 32, 12), blk, 0, stream>>>(wk, WT + 1024*1024,   DD, DD, DD, (size_t)DD*DD, LWT);
    k_wtrans<<<dim3(4, 32, 12), blk, 0, stream>>>(wv, WT + 2048*1024,   DD, DD, DD, (size_t)DD*DD, LWT);
    k_wtrans<<<dim3(4, 32, 12), blk, 0, stream>>>(wo, WT + 3145728,     DD, DD, DD, (size_t)DD*DD, LWT);
    k_wtrans<<<dim3(16, 32, 12), blk, 0, stream>>>(w1, WT + 4194304,    DD, FF, FF, (size_t)DD*FF, LWT);
    k_wtrans<<<dim3(4, 128, 12), blk, 0, stream>>>(w2, WT + 8388608,    FF, DD, DD, (size_t)FF*DD, LWT);
    if (fast_logits)
        k_wtrans<<<dim3(VP/256, 32, 1), blk, 0, stream>>>(fcw, fcwT, DD, VV, VP, 0, 0);
    k_biasmerge<<<dim3(144), blk, 0, stream>>>(bq, bk, bv, bqkv);

    // ---- trunk (residual-add fused into LN) ----
    k_embed<<<MM, blk, 0, stream>>>(x, tok, pos, hB);
    for (int l = 0; l < LL; l++) {
        const bf16* WTl = WT + (size_t)l * LWT;
        k_lnadd<<<MM/4, blk, 0, stream>>>(hB, l ? fout : nullptr,
                                          ln1g + l*DD, ln1b + l*DD, hA, hnb);
        k_gemm3<<<dim3(QS/256, MM/256), blk512, 0, stream>>>(hnb, WTl, bqkv + l*QS,
                                                  nullptr, nullptr, qkv, DD, QS, 0, 0, 1);
        k_attn4<<<dim3(TT/256, BB*HH), blk512, 0, stream>>>(qkv, obuf);
        k_gemm2t<64><<<dim3(8, 64), blk, 0, stream>>>(obuf, WTl + 3145728, bo + l*DD,
                                                 nullptr, nullptr, pb, DD, DD, 0, 0, 0);
        k_lnadd<<<MM/4, blk, 0, stream>>>(hA, pb, ln2g + l*DD, ln2b + l*DD, hB, hnb);
        k_gemm3<<<dim3(FF/256, MM/256), blk512, 0, stream>>>(hnb, WTl + 4194304, b1 + l*FF,
                                                  nullptr, nullptr, f1b, DD, FF, 1, 0, 0);
        k_gemm2t<64><<<dim3(8, 64), blk, 0, stream>>>(f1b, WTl + 8388608, b2 + l*DD,
                                                 nullptr, nullptr, fout, FF, DD, 0, 0, 0);
    }
    k_lnadd<<<MM/4, blk, 0, stream>>>(hB, fout, lnfg, lnfb, nullptr, hfb);

    // ---- logits (m-fastest grid, regular stores) ----
    if (fast_logits) {
        k_gemm3<<<dim3(MM/256, VP/256), blk512, 0, stream>>>(hfb, fcwT, fcb,
                                                      nullptr, (float*)d_out, nullptr,
                                                      DD, VV, 0, 1, 0);
    } else {
        k_gemm_f32b<<<dim3(32, (VV + 127)/128), blk, 0, stream>>>(hfb, fcw, fcb,
                                                                  (float*)d_out, MM, VV, DD);
    }
}